// Round 5
// baseline (308.820 us; speedup 1.0000x reference)
//
#include <hip/hip_runtime.h>

#define NBLOCKS 4096
#define WPB 4
#define BLOCK 256

typedef __attribute__((ext_vector_type(8))) short sh8;
typedef __attribute__((ext_vector_type(4))) float f32x4;

__device__ __forceinline__ float sel4(int b, float x0, float x1, float x2, float x3) {
    float r = x3;
    r = (b == 2) ? x2 : r;
    r = (b == 1) ? x1 : r;
    r = (b == 0) ? x0 : r;
    return r;
}

__device__ __forceinline__ float fast_tanh(float x) {
    float e = __expf(2.f * x);
    return 1.f - 2.f / (e + 1.f);
}

__device__ __forceinline__ float wred(float v) {
    v += __shfl_xor(v, 32, 64);
    v += __shfl_xor(v, 16, 64);
    v += __shfl_xor(v, 8, 64);
    v += __shfl_xor(v, 4, 64);
    v += __shfl_xor(v, 2, 64);
    v += __shfl_xor(v, 1, 64);
    return v;
}

// swizzled bf16 index into a [rows][64] LDS array (row stride = 32 dwords).
__device__ __forceinline__ int zidx(int m, int u) {
    return (((m << 5) + (((u >> 1) ^ ((m & 7) << 2)))) << 1) + (u & 1);
}

// load an 8x-bf16 MFMA fragment: row = matrix row, lanes' k-slice = kt*32 + g*8
__device__ __forceinline__ sh8 ldfrag(const unsigned short* base, int row, int g, int kt) {
    const int dw = (row << 5) + ((((kt << 4) + (g << 2))) ^ ((row & 7) << 2));
    return *(const sh8*)(base + (dw << 1));
}

// split f32 into truncated-bf16 hi and bf16(x-hi) lo
__device__ __forceinline__ void wsplit(float x, unsigned short& h, unsigned short& l) {
    const unsigned ub = __float_as_uint(x);
    const unsigned hb = ub & 0xffff0000u;
    const float lf = x - __uint_as_float(hb);
    h = (unsigned short)(hb >> 16);
    l = (unsigned short)(__float_as_uint(lf) >> 16);
}

__global__ __launch_bounds__(BLOCK, 5) void einstein_kernel(
    const float* __restrict__ coords,
    const float* __restrict__ gW1, const float* __restrict__ gb1,
    const float* __restrict__ gW2, const float* __restrict__ gb2,
    const float* __restrict__ gW3, const float* __restrict__ gb3,
    const float* __restrict__ gW4, const float* __restrict__ gb4,
    float* __restrict__ out, int B)
{
    // weights transposed+swizzled: [layer][out 64][in 64] bf16 (hi staged first,
    // pulled to regs, then overwritten with lo residual)
    __shared__ __align__(16) unsigned short wlds[2][4096];
    // per-wave 4 KB region, time-multiplexed:
    //   phase A: zh = bf16-hi state [0..1023], zl = bf16-lo state [1024..2047]
    //   phase B: cb = f32 scatter/gather [15][68]  (aliases zh+zl)
    //   phase C: epilogue gmB/dgmB/rcB/fkB (352 f32, aliases same region)
    __shared__ __align__(16) unsigned short zS[WPB][2048];

    const int wv = threadIdx.x >> 6;
    const int lane = threadIdx.x & 63;
    const int n15 = lane & 15;
    const int g4 = lane >> 4;
    unsigned short* zh = zS[wv];
    unsigned short* zl = zS[wv] + 1024;
    float* cb = (float*)zS[wv];
    float* gmB = cb;          // 64
    float* dgmB = cb + 64;    // 256
    float* rcB = cb + 320;    // 16
    float* fkB = cb + 336;    // 16

    // ---- stage Wh (truncated-bf16) into LDS, pull fragments to registers ----
    for (int e = threadIdx.x; e < 4096; e += BLOCK) {
        const int o = e & 63, i = e >> 6;
        unsigned short h2, l2, h3, l3;
        wsplit(gW2[i * 64 + o], h2, l2);
        wsplit(gW3[i * 64 + o], h3, l3);
        const int ix = zidx(o, i);
        wlds[0][ix] = h2;
        wlds[1][ix] = h3;
    }
    __syncthreads();
    sh8 Whf[2][4][2];
    #pragma unroll
    for (int L = 0; L < 2; ++L)
        #pragma unroll
        for (int nt = 0; nt < 4; ++nt)
            #pragma unroll
            for (int kt = 0; kt < 2; ++kt)
                Whf[L][nt][kt] = ldfrag(wlds[L], nt * 16 + n15, g4, kt);
    __syncthreads();
    // ---- restage with Wl (low bf16 residual) ----
    for (int e = threadIdx.x; e < 4096; e += BLOCK) {
        const int o = e & 63, i = e >> 6;
        unsigned short h2, l2, h3, l3;
        wsplit(gW2[i * 64 + o], h2, l2);
        wsplit(gW3[i * 64 + o], h3, l3);
        const int ix = zidx(o, i);
        wlds[0][ix] = l2;
        wlds[1][ix] = l3;
    }
    __syncthreads();
    // NOTE: A-row 15 (jet 15) is never zeroed: it holds garbage from the cb
    // alias. MFMA rows are independent, so garbage stays in C row 15, which
    // is never read (gather uses m<15 only).

    // per-lane layer-1 constants (lane = hidden unit)
    const float w1c0 = gW1[0 * 64 + lane];
    const float w1c1 = gW1[1 * 64 + lane];
    const float w1c2 = gW1[2 * 64 + lane];
    const float w1c3 = gW1[3 * 64 + lane];
    const float b1c = gb1[lane], b2c = gb2[lane], b3c = gb3[lane];
    const float w4c = gW4[lane];
    const float b4v = gb4[0];

    const int wid = blockIdx.x * WPB + wv;
    const int nw = NBLOCKS * WPB;

    for (int p = wid; p < B; p += nw) {
        const float4 c4 = reinterpret_cast<const float4*>(coords)[p];
        const float cr = c4.y, cth = c4.z;

        float z[15];
        // ---------- layer 1 (4 -> 64), closed-form jet, lane = unit
        {
            const float u = b1c + c4.x * w1c0 + cr * w1c1 + cth * w1c2 + c4.w * w1c3;
            const float y = fast_tanh(u);
            const float D = 1.f - y * y;
            const float m2 = -2.f * y * D;
            z[0] = y;
            z[1] = D * w1c0; z[2] = D * w1c1; z[3] = D * w1c2; z[4] = D * w1c3;
            z[5] = m2 * w1c0 * w1c0; z[6] = m2 * w1c0 * w1c1; z[7] = m2 * w1c0 * w1c2; z[8] = m2 * w1c0 * w1c3;
            z[9] = m2 * w1c1 * w1c1; z[10] = m2 * w1c1 * w1c2; z[11] = m2 * w1c1 * w1c3;
            z[12] = m2 * w1c2 * w1c2; z[13] = m2 * w1c2 * w1c3; z[14] = m2 * w1c3 * w1c3;
        }
        #pragma unroll
        for (int m = 0; m < 15; ++m) {
            unsigned short h, l;
            wsplit(z[m], h, l);
            const int ix = zidx(m, lane);
            zh[ix] = h;
            zl[ix] = l;
        }
        asm volatile("s_waitcnt lgkmcnt(0)" ::: "memory");

        // ---------- layers 2,3: jet-GEMM on MFMA with hi/lo split
        #pragma unroll
        for (int LL = 0; LL < 2; ++LL) {
            const unsigned short* wl = wlds[LL];
            const sh8 Ah0 = ldfrag(zh, n15, g4, 0);
            const sh8 Ah1 = ldfrag(zh, n15, g4, 1);
            const sh8 Al0 = ldfrag(zl, n15, g4, 0);
            const sh8 Al1 = ldfrag(zl, n15, g4, 1);
            f32x4 acc[4];
            #pragma unroll
            for (int nt = 0; nt < 4; ++nt) {
                f32x4 a0 = {0.f, 0.f, 0.f, 0.f};
                const sh8 Bl0 = ldfrag(wl, nt * 16 + n15, g4, 0);
                const sh8 Bl1 = ldfrag(wl, nt * 16 + n15, g4, 1);
                a0 = __builtin_amdgcn_mfma_f32_16x16x32_bf16(Ah0, Whf[LL][nt][0], a0, 0, 0, 0);
                a0 = __builtin_amdgcn_mfma_f32_16x16x32_bf16(Ah1, Whf[LL][nt][1], a0, 0, 0, 0);
                a0 = __builtin_amdgcn_mfma_f32_16x16x32_bf16(Al0, Whf[LL][nt][0], a0, 0, 0, 0);
                a0 = __builtin_amdgcn_mfma_f32_16x16x32_bf16(Al1, Whf[LL][nt][1], a0, 0, 0, 0);
                a0 = __builtin_amdgcn_mfma_f32_16x16x32_bf16(Ah0, Bl0, a0, 0, 0, 0);
                a0 = __builtin_amdgcn_mfma_f32_16x16x32_bf16(Ah1, Bl1, a0, 0, 0, 0);
                acc[nt] = a0;
            }
            // scatter C (jet m = g4*4+j, unit = nt*16+n15) into cb (aliases zh/zl,
            // safe: A-frags already in regs). Row 15 (g4==3,j==3) masked: it
            // would overflow the 4 KB window and is garbage anyway.
            asm volatile("s_waitcnt lgkmcnt(0)" ::: "memory");
            #pragma unroll
            for (int nt = 0; nt < 4; ++nt)
                #pragma unroll
                for (int j = 0; j < 4; ++j)
                    if (!(g4 == 3 && j == 3))
                        cb[(g4 * 4 + j) * 68 + nt * 16 + n15] = acc[nt][j];
            asm volatile("s_waitcnt lgkmcnt(0)" ::: "memory");
            // gather: lane = unit, all 15 jets
            float a[15];
            #pragma unroll
            for (int m = 0; m < 15; ++m) a[m] = cb[m * 68 + lane];
            asm volatile("s_waitcnt lgkmcnt(0)" ::: "memory");   // gather retired before z-write clobbers

            const float a0v = a[0] + (LL ? b3c : b2c);
            const float y = fast_tanh(a0v);
            const float D = 1.f - y * y;
            const float m2 = -2.f * y * D;
            z[0] = y;
            z[1] = D * a[1]; z[2] = D * a[2]; z[3] = D * a[3]; z[4] = D * a[4];
            z[5] = D * a[5] + m2 * a[1] * a[1];
            z[6] = D * a[6] + m2 * a[1] * a[2];
            z[7] = D * a[7] + m2 * a[1] * a[3];
            z[8] = D * a[8] + m2 * a[1] * a[4];
            z[9] = D * a[9] + m2 * a[2] * a[2];
            z[10] = D * a[10] + m2 * a[2] * a[3];
            z[11] = D * a[11] + m2 * a[2] * a[4];
            z[12] = D * a[12] + m2 * a[3] * a[3];
            z[13] = D * a[13] + m2 * a[3] * a[4];
            z[14] = D * a[14] + m2 * a[4] * a[4];

            if (LL == 0) {
                #pragma unroll
                for (int m = 0; m < 15; ++m) {
                    unsigned short h, l;
                    wsplit(z[m], h, l);
                    const int ix = zidx(m, lane);
                    zh[ix] = h;
                    zl[ix] = l;
                }
                asm volatile("s_waitcnt lgkmcnt(0)" ::: "memory");
            }
        }

        // ---------- final linear layer (64 -> 1): wave reductions
        const float f = wred(w4c * z[0]) + b4v;
        const float fj0 = wred(w4c * z[1]);
        const float fj1 = wred(w4c * z[2]);
        const float fj2 = wred(w4c * z[3]);
        const float fj3 = wred(w4c * z[4]);
        const float s00 = wred(w4c * z[5]);
        const float s01 = wred(w4c * z[6]);
        const float s02 = wred(w4c * z[7]);
        const float s03 = wred(w4c * z[8]);
        const float s11 = wred(w4c * z[9]);
        const float s12 = wred(w4c * z[10]);
        const float s13 = wred(w4c * z[11]);
        const float s22 = wred(w4c * z[12]);
        const float s23 = wred(w4c * z[13]);
        const float s33 = wred(w4c * z[14]);

        // ---------- analytic Einstein tensor
        float S, Cq;
        __sincosf(cth, &S, &Cq);
        const float E = __expf(f);
        const float r2v = cr * cr, S2 = S * S;
        const float GI1 = 1.f / E;
        const float GI2 = 1.f / r2v;
        const float GI3 = GI2 / S2;
        const float d3_r = 2.f * cr * S2;
        const float d3_th = 2.f * r2v * S * Cq;
        const float dd_rr = 2.f * S2;
        const float dd_rth = 4.f * cr * S * Cq;
        const float dd_thth = 2.f * r2v * (Cq * Cq - S2);

        if (lane < 16) {
            const int jj = lane >> 2, kk = lane & 3;
            const int lo = jj < kk ? jj : kk, hi = jj < kk ? kk : jj;
            const int code = lo * 4 + hi;
            float v = s33;
            v = code == 0 ? s00 : v;  v = code == 1 ? s01 : v;  v = code == 2 ? s02 : v;
            v = code == 3 ? s03 : v;  v = code == 5 ? s11 : v;  v = code == 6 ? s12 : v;
            v = code == 7 ? s13 : v;  v = code == 10 ? s22 : v; v = code == 11 ? s23 : v;
            fkB[lane] = v;
        }
        asm volatile("s_waitcnt lgkmcnt(0)" ::: "memory");

        auto fjsel = [&](int b) { return sel4(b, fj0, fj1, fj2, fj3); };
        auto dgd = [&](int a, int b) {
            float v1 = E * fjsel(b);
            float v2 = (b == 1) ? (2.f * cr) : 0.f;
            float v3 = (b == 1) ? d3_r : ((b == 2) ? d3_th : 0.f);
            return (a == 1) ? v1 : ((a == 2) ? v2 : ((a == 3) ? v3 : 0.f));
        };
        auto d2f = [&](int a, int b, int l) {
            float v1 = E * (fjsel(b) * fjsel(l) + fkB[b * 4 + l]);
            float v2 = (b == 1 && l == 1) ? 2.f : 0.f;
            float v3 = (b == 1 && l == 1) ? dd_rr
                       : (((b == 1 && l == 2) || (b == 2 && l == 1)) ? dd_rth
                       : ((b == 2 && l == 2) ? dd_thth : 0.f));
            return (a == 1) ? v1 : ((a == 2) ? v2 : ((a == 3) ? v3 : 0.f));
        };

        const int li = (lane >> 4) & 3, lk = (lane >> 2) & 3, lj = lane & 3;
        const float GIi = sel4(li, -1.f, GI1, GI2, GI3);
        float P = (lk == li ? dgd(li, lj) : 0.f)
                + (lj == li ? dgd(li, lk) : 0.f)
                - (lj == lk ? dgd(lj, li) : 0.f);
        gmB[lane] = 0.5f * GIi * P;
        const float GIi2 = GIi * GIi;
        float dgm0, dgm1, dgm2, dgm3;
        {
            float Q0 = (lk == li ? d2f(li, lj, 0) : 0.f) + (lj == li ? d2f(li, lk, 0) : 0.f) - (lj == lk ? d2f(lj, li, 0) : 0.f);
            float Q1 = (lk == li ? d2f(li, lj, 1) : 0.f) + (lj == li ? d2f(li, lk, 1) : 0.f) - (lj == lk ? d2f(lj, li, 1) : 0.f);
            float Q2 = (lk == li ? d2f(li, lj, 2) : 0.f) + (lj == li ? d2f(li, lk, 2) : 0.f) - (lj == lk ? d2f(lj, li, 2) : 0.f);
            float Q3 = (lk == li ? d2f(li, lj, 3) : 0.f) + (lj == li ? d2f(li, lk, 3) : 0.f) - (lj == lk ? d2f(lj, li, 3) : 0.f);
            dgm0 = 0.5f * (GIi * Q0 - dgd(li, 0) * GIi2 * P);
            dgm1 = 0.5f * (GIi * Q1 - dgd(li, 1) * GIi2 * P);
            dgm2 = 0.5f * (GIi * Q2 - dgd(li, 2) * GIi2 * P);
            dgm3 = 0.5f * (GIi * Q3 - dgd(li, 3) * GIi2 * P);
        }
        reinterpret_cast<float4*>(dgmB)[lane] = make_float4(dgm0, dgm1, dgm2, dgm3);
        asm volatile("s_waitcnt lgkmcnt(0)" ::: "memory");

        if (lane < 16) {
            const int j = lane >> 2, k = lane & 3;
            float T0 = 0, T1 = 0, T2 = 0, T3 = 0;
            #pragma unroll
            for (int i = 0; i < 4; ++i) {
                T0 += gmB[i * 16 + 0 + i];
                T1 += gmB[i * 16 + 4 + i];
                T2 += gmB[i * 16 + 8 + i];
                T3 += gmB[i * 16 + 12 + i];
            }
            float t1 = gmB[0 + j * 4 + k] * T0 + gmB[16 + j * 4 + k] * T1
                     + gmB[32 + j * 4 + k] * T2 + gmB[48 + j * 4 + k] * T3;
            float t2 = 0.f;
            #pragma unroll
            for (int m = 0; m < 4; ++m) {
                #pragma unroll
                for (int i = 0; i < 4; ++i)
                    t2 += gmB[m * 16 + j * 4 + i] * gmB[i * 16 + m * 4 + k];
            }
            float t3 = 0.f, t4 = 0.f;
            #pragma unroll
            for (int i = 0; i < 4; ++i) {
                t3 += dgmB[(i * 16 + j * 4 + k) * 4 + i];
                t4 += dgmB[(i * 16 + j * 4 + i) * 4 + k];
            }
            rcB[lane] = t1 - t2 + t3 - t4;
        }
        asm volatile("s_waitcnt lgkmcnt(0)" ::: "memory");

        if (lane < 16) {
            const int j = lane >> 2, k = lane & 3;
            const float R = -rcB[0] + GI1 * rcB[5] + GI2 * rcB[10] + GI3 * rcB[15];
            const float GIj = sel4(j, -1.f, GI1, GI2, GI3);
            const float GIk = sel4(k, -1.f, GI1, GI2, GI3);
            const float o = GIj * GIk * rcB[lane] - ((j == k) ? 0.5f * R * GIj : 0.f);
            out[p * 16 + lane] = o;
        }
        asm volatile("s_waitcnt lgkmcnt(0)" ::: "memory");   // rcB reads retired before next point's z-write
    }
}

extern "C" void kernel_launch(void* const* d_in, const int* in_sizes, int n_in,
                              void* d_out, int out_size, void* d_ws, size_t ws_size,
                              hipStream_t stream) {
    const float* coords = (const float*)d_in[0];
    const float* W1 = (const float*)d_in[1];
    const float* b1 = (const float*)d_in[2];
    const float* W2 = (const float*)d_in[3];
    const float* b2 = (const float*)d_in[4];
    const float* W3 = (const float*)d_in[5];
    const float* b3 = (const float*)d_in[6];
    const float* W4 = (const float*)d_in[7];
    const float* b4 = (const float*)d_in[8];
    const int B = in_sizes[0] / 4;

    hipLaunchKernelGGL(einstein_kernel, dim3(NBLOCKS), dim3(BLOCK), 0, stream,
                       coords, W1, b1, W2, b2, W3, b3, W4, b4,
                       (float*)d_out, B);
}

// Round 6
// 181.094 us; speedup vs baseline: 1.7053x; 1.7053x over previous
//
#include <hip/hip_runtime.h>

#define NBLOCKS 4096
#define WPB 4
#define BLOCK 256

typedef __attribute__((ext_vector_type(8))) short sh8;
typedef __attribute__((ext_vector_type(4))) float f32x4;

__device__ __forceinline__ float sel4(int b, float x0, float x1, float x2, float x3) {
    float r = x3;
    r = (b == 2) ? x2 : r;
    r = (b == 1) ? x1 : r;
    r = (b == 0) ? x0 : r;
    return r;
}

__device__ __forceinline__ float fast_tanh(float x) {
    float e = __expf(2.f * x);
    return 1.f - 2.f / (e + 1.f);
}

__device__ __forceinline__ float wred(float v) {
    v += __shfl_xor(v, 32, 64);
    v += __shfl_xor(v, 16, 64);
    v += __shfl_xor(v, 8, 64);
    v += __shfl_xor(v, 4, 64);
    v += __shfl_xor(v, 2, 64);
    v += __shfl_xor(v, 1, 64);
    return v;
}

// swizzled bf16 index into a [rows][64] LDS array (row stride = 32 dwords).
__device__ __forceinline__ int zidx(int m, int u) {
    return (((m << 5) + (((u >> 1) ^ ((m & 7) << 2)))) << 1) + (u & 1);
}

// load an 8x-bf16 MFMA fragment: row = matrix row, lanes' k-slice = kt*32 + g*8
__device__ __forceinline__ sh8 ldfrag(const unsigned short* base, int row, int g, int kt) {
    const int dw = (row << 5) + ((((kt << 4) + (g << 2))) ^ ((row & 7) << 2));
    return *(const sh8*)(base + (dw << 1));
}

// split f32 into truncated-bf16 hi and bf16(x-hi) lo
__device__ __forceinline__ void wsplit(float x, unsigned short& h, unsigned short& l) {
    const unsigned ub = __float_as_uint(x);
    const unsigned hb = ub & 0xffff0000u;
    const float lf = x - __uint_as_float(hb);
    h = (unsigned short)(hb >> 16);
    l = (unsigned short)(__float_as_uint(lf) >> 16);
}

// launch_bounds(256,4): VGPR cap 128 — kernel needs ~84-100 (Whf frags = 64).
// (256,5) capped at 102 and the allocator SPILLED Whf to scratch: 930 MB/dispatch
// of HBM scratch traffic, 308 us (R5). Do not tighten past the spill cliff.
__global__ __launch_bounds__(BLOCK, 4) void einstein_kernel(
    const float* __restrict__ coords,
    const float* __restrict__ gW1, const float* __restrict__ gb1,
    const float* __restrict__ gW2, const float* __restrict__ gb2,
    const float* __restrict__ gW3, const float* __restrict__ gb3,
    const float* __restrict__ gW4, const float* __restrict__ gb4,
    float* __restrict__ out, int B)
{
    // weights transposed+swizzled: [layer][out 64][in 64] bf16 (hi staged first,
    // pulled to regs, then overwritten with lo residual)
    __shared__ __align__(16) unsigned short wlds[2][4096];
    // per-wave 4 KB region, time-multiplexed:
    //   phase A: zh = bf16-hi state [0..1023], zl = bf16-lo state [1024..2047]
    //   phase B: cb = f32 scatter/gather [15][68]  (aliases zh+zl)
    //   phase C: epilogue gmB/dgmB/rcB/fkB (352 f32, aliases same region)
    __shared__ __align__(16) unsigned short zS[WPB][2048];

    const int wv = threadIdx.x >> 6;
    const int lane = threadIdx.x & 63;
    const int n15 = lane & 15;
    const int g4 = lane >> 4;
    unsigned short* zh = zS[wv];
    unsigned short* zl = zS[wv] + 1024;
    float* cb = (float*)zS[wv];
    float* gmB = cb;          // 64
    float* dgmB = cb + 64;    // 256
    float* rcB = cb + 320;    // 16
    float* fkB = cb + 336;    // 16

    // ---- stage Wh (truncated-bf16) into LDS, pull fragments to registers ----
    for (int e = threadIdx.x; e < 4096; e += BLOCK) {
        const int o = e & 63, i = e >> 6;
        unsigned short h2, l2, h3, l3;
        wsplit(gW2[i * 64 + o], h2, l2);
        wsplit(gW3[i * 64 + o], h3, l3);
        const int ix = zidx(o, i);
        wlds[0][ix] = h2;
        wlds[1][ix] = h3;
    }
    __syncthreads();
    sh8 Whf[2][4][2];
    #pragma unroll
    for (int L = 0; L < 2; ++L)
        #pragma unroll
        for (int nt = 0; nt < 4; ++nt)
            #pragma unroll
            for (int kt = 0; kt < 2; ++kt)
                Whf[L][nt][kt] = ldfrag(wlds[L], nt * 16 + n15, g4, kt);
    __syncthreads();
    // ---- restage with Wl (low bf16 residual) ----
    for (int e = threadIdx.x; e < 4096; e += BLOCK) {
        const int o = e & 63, i = e >> 6;
        unsigned short h2, l2, h3, l3;
        wsplit(gW2[i * 64 + o], h2, l2);
        wsplit(gW3[i * 64 + o], h3, l3);
        const int ix = zidx(o, i);
        wlds[0][ix] = l2;
        wlds[1][ix] = l3;
    }
    __syncthreads();
    // NOTE: A-row 15 (jet 15) is never zeroed: it holds garbage from the cb
    // alias. MFMA rows are independent, so garbage stays in C row 15, which
    // is never read (gather uses m<15 only).

    // per-lane layer-1 constants (lane = hidden unit)
    const float w1c0 = gW1[0 * 64 + lane];
    const float w1c1 = gW1[1 * 64 + lane];
    const float w1c2 = gW1[2 * 64 + lane];
    const float w1c3 = gW1[3 * 64 + lane];
    const float b1c = gb1[lane], b2c = gb2[lane], b3c = gb3[lane];
    const float w4c = gW4[lane];
    const float b4v = gb4[0];

    const int wid = blockIdx.x * WPB + wv;
    const int nw = NBLOCKS * WPB;

    for (int p = wid; p < B; p += nw) {
        const float4 c4 = reinterpret_cast<const float4*>(coords)[p];
        const float cr = c4.y, cth = c4.z;

        float z[15];
        // ---------- layer 1 (4 -> 64), closed-form jet, lane = unit
        {
            const float u = b1c + c4.x * w1c0 + cr * w1c1 + cth * w1c2 + c4.w * w1c3;
            const float y = fast_tanh(u);
            const float D = 1.f - y * y;
            const float m2 = -2.f * y * D;
            z[0] = y;
            z[1] = D * w1c0; z[2] = D * w1c1; z[3] = D * w1c2; z[4] = D * w1c3;
            z[5] = m2 * w1c0 * w1c0; z[6] = m2 * w1c0 * w1c1; z[7] = m2 * w1c0 * w1c2; z[8] = m2 * w1c0 * w1c3;
            z[9] = m2 * w1c1 * w1c1; z[10] = m2 * w1c1 * w1c2; z[11] = m2 * w1c1 * w1c3;
            z[12] = m2 * w1c2 * w1c2; z[13] = m2 * w1c2 * w1c3; z[14] = m2 * w1c3 * w1c3;
        }
        #pragma unroll
        for (int m = 0; m < 15; ++m) {
            unsigned short h, l;
            wsplit(z[m], h, l);
            const int ix = zidx(m, lane);
            zh[ix] = h;
            zl[ix] = l;
        }
        asm volatile("s_waitcnt lgkmcnt(0)" ::: "memory");

        // ---------- layers 2,3: jet-GEMM on MFMA with hi/lo split
        #pragma unroll
        for (int LL = 0; LL < 2; ++LL) {
            const unsigned short* wl = wlds[LL];
            const sh8 Ah0 = ldfrag(zh, n15, g4, 0);
            const sh8 Ah1 = ldfrag(zh, n15, g4, 1);
            const sh8 Al0 = ldfrag(zl, n15, g4, 0);
            const sh8 Al1 = ldfrag(zl, n15, g4, 1);
            f32x4 acc[4];
            #pragma unroll
            for (int nt = 0; nt < 4; ++nt) {
                f32x4 a0 = {0.f, 0.f, 0.f, 0.f};
                const sh8 Bl0 = ldfrag(wl, nt * 16 + n15, g4, 0);
                const sh8 Bl1 = ldfrag(wl, nt * 16 + n15, g4, 1);
                a0 = __builtin_amdgcn_mfma_f32_16x16x32_bf16(Ah0, Whf[LL][nt][0], a0, 0, 0, 0);
                a0 = __builtin_amdgcn_mfma_f32_16x16x32_bf16(Ah1, Whf[LL][nt][1], a0, 0, 0, 0);
                a0 = __builtin_amdgcn_mfma_f32_16x16x32_bf16(Al0, Whf[LL][nt][0], a0, 0, 0, 0);
                a0 = __builtin_amdgcn_mfma_f32_16x16x32_bf16(Al1, Whf[LL][nt][1], a0, 0, 0, 0);
                a0 = __builtin_amdgcn_mfma_f32_16x16x32_bf16(Ah0, Bl0, a0, 0, 0, 0);
                a0 = __builtin_amdgcn_mfma_f32_16x16x32_bf16(Ah1, Bl1, a0, 0, 0, 0);
                acc[nt] = a0;
            }
            // scatter C (jet m = g4*4+j, unit = nt*16+n15) into cb (aliases zh/zl,
            // safe: A-frags already in regs). Row 15 (g4==3,j==3) masked: it
            // would overflow the 4 KB window and is garbage anyway.
            asm volatile("s_waitcnt lgkmcnt(0)" ::: "memory");
            #pragma unroll
            for (int nt = 0; nt < 4; ++nt)
                #pragma unroll
                for (int j = 0; j < 4; ++j)
                    if (!(g4 == 3 && j == 3))
                        cb[(g4 * 4 + j) * 68 + nt * 16 + n15] = acc[nt][j];
            asm volatile("s_waitcnt lgkmcnt(0)" ::: "memory");
            // gather: lane = unit, all 15 jets
            float a[15];
            #pragma unroll
            for (int m = 0; m < 15; ++m) a[m] = cb[m * 68 + lane];
            asm volatile("s_waitcnt lgkmcnt(0)" ::: "memory");   // gather retired before z-write clobbers

            const float a0v = a[0] + (LL ? b3c : b2c);
            const float y = fast_tanh(a0v);
            const float D = 1.f - y * y;
            const float m2 = -2.f * y * D;
            z[0] = y;
            z[1] = D * a[1]; z[2] = D * a[2]; z[3] = D * a[3]; z[4] = D * a[4];
            z[5] = D * a[5] + m2 * a[1] * a[1];
            z[6] = D * a[6] + m2 * a[1] * a[2];
            z[7] = D * a[7] + m2 * a[1] * a[3];
            z[8] = D * a[8] + m2 * a[1] * a[4];
            z[9] = D * a[9] + m2 * a[2] * a[2];
            z[10] = D * a[10] + m2 * a[2] * a[3];
            z[11] = D * a[11] + m2 * a[2] * a[4];
            z[12] = D * a[12] + m2 * a[3] * a[3];
            z[13] = D * a[13] + m2 * a[3] * a[4];
            z[14] = D * a[14] + m2 * a[4] * a[4];

            if (LL == 0) {
                #pragma unroll
                for (int m = 0; m < 15; ++m) {
                    unsigned short h, l;
                    wsplit(z[m], h, l);
                    const int ix = zidx(m, lane);
                    zh[ix] = h;
                    zl[ix] = l;
                }
                asm volatile("s_waitcnt lgkmcnt(0)" ::: "memory");
            }
        }

        // ---------- final linear layer (64 -> 1): wave reductions
        const float f = wred(w4c * z[0]) + b4v;
        const float fj0 = wred(w4c * z[1]);
        const float fj1 = wred(w4c * z[2]);
        const float fj2 = wred(w4c * z[3]);
        const float fj3 = wred(w4c * z[4]);
        const float s00 = wred(w4c * z[5]);
        const float s01 = wred(w4c * z[6]);
        const float s02 = wred(w4c * z[7]);
        const float s03 = wred(w4c * z[8]);
        const float s11 = wred(w4c * z[9]);
        const float s12 = wred(w4c * z[10]);
        const float s13 = wred(w4c * z[11]);
        const float s22 = wred(w4c * z[12]);
        const float s23 = wred(w4c * z[13]);
        const float s33 = wred(w4c * z[14]);

        // ---------- analytic Einstein tensor
        float S, Cq;
        __sincosf(cth, &S, &Cq);
        const float E = __expf(f);
        const float r2v = cr * cr, S2 = S * S;
        const float GI1 = 1.f / E;
        const float GI2 = 1.f / r2v;
        const float GI3 = GI2 / S2;
        const float d3_r = 2.f * cr * S2;
        const float d3_th = 2.f * r2v * S * Cq;
        const float dd_rr = 2.f * S2;
        const float dd_rth = 4.f * cr * S * Cq;
        const float dd_thth = 2.f * r2v * (Cq * Cq - S2);

        if (lane < 16) {
            const int jj = lane >> 2, kk = lane & 3;
            const int lo = jj < kk ? jj : kk, hi = jj < kk ? kk : jj;
            const int code = lo * 4 + hi;
            float v = s33;
            v = code == 0 ? s00 : v;  v = code == 1 ? s01 : v;  v = code == 2 ? s02 : v;
            v = code == 3 ? s03 : v;  v = code == 5 ? s11 : v;  v = code == 6 ? s12 : v;
            v = code == 7 ? s13 : v;  v = code == 10 ? s22 : v; v = code == 11 ? s23 : v;
            fkB[lane] = v;
        }
        asm volatile("s_waitcnt lgkmcnt(0)" ::: "memory");

        auto fjsel = [&](int b) { return sel4(b, fj0, fj1, fj2, fj3); };
        auto dgd = [&](int a, int b) {
            float v1 = E * fjsel(b);
            float v2 = (b == 1) ? (2.f * cr) : 0.f;
            float v3 = (b == 1) ? d3_r : ((b == 2) ? d3_th : 0.f);
            return (a == 1) ? v1 : ((a == 2) ? v2 : ((a == 3) ? v3 : 0.f));
        };
        auto d2f = [&](int a, int b, int l) {
            float v1 = E * (fjsel(b) * fjsel(l) + fkB[b * 4 + l]);
            float v2 = (b == 1 && l == 1) ? 2.f : 0.f;
            float v3 = (b == 1 && l == 1) ? dd_rr
                       : (((b == 1 && l == 2) || (b == 2 && l == 1)) ? dd_rth
                       : ((b == 2 && l == 2) ? dd_thth : 0.f));
            return (a == 1) ? v1 : ((a == 2) ? v2 : ((a == 3) ? v3 : 0.f));
        };

        const int li = (lane >> 4) & 3, lk = (lane >> 2) & 3, lj = lane & 3;
        const float GIi = sel4(li, -1.f, GI1, GI2, GI3);
        float P = (lk == li ? dgd(li, lj) : 0.f)
                + (lj == li ? dgd(li, lk) : 0.f)
                - (lj == lk ? dgd(lj, li) : 0.f);
        gmB[lane] = 0.5f * GIi * P;
        const float GIi2 = GIi * GIi;
        float dgm0, dgm1, dgm2, dgm3;
        {
            float Q0 = (lk == li ? d2f(li, lj, 0) : 0.f) + (lj == li ? d2f(li, lk, 0) : 0.f) - (lj == lk ? d2f(lj, li, 0) : 0.f);
            float Q1 = (lk == li ? d2f(li, lj, 1) : 0.f) + (lj == li ? d2f(li, lk, 1) : 0.f) - (lj == lk ? d2f(lj, li, 1) : 0.f);
            float Q2 = (lk == li ? d2f(li, lj, 2) : 0.f) + (lj == li ? d2f(li, lk, 2) : 0.f) - (lj == lk ? d2f(lj, li, 2) : 0.f);
            float Q3 = (lk == li ? d2f(li, lj, 3) : 0.f) + (lj == li ? d2f(li, lk, 3) : 0.f) - (lj == lk ? d2f(lj, li, 3) : 0.f);
            dgm0 = 0.5f * (GIi * Q0 - dgd(li, 0) * GIi2 * P);
            dgm1 = 0.5f * (GIi * Q1 - dgd(li, 1) * GIi2 * P);
            dgm2 = 0.5f * (GIi * Q2 - dgd(li, 2) * GIi2 * P);
            dgm3 = 0.5f * (GIi * Q3 - dgd(li, 3) * GIi2 * P);
        }
        reinterpret_cast<float4*>(dgmB)[lane] = make_float4(dgm0, dgm1, dgm2, dgm3);
        asm volatile("s_waitcnt lgkmcnt(0)" ::: "memory");

        if (lane < 16) {
            const int j = lane >> 2, k = lane & 3;
            float T0 = 0, T1 = 0, T2 = 0, T3 = 0;
            #pragma unroll
            for (int i = 0; i < 4; ++i) {
                T0 += gmB[i * 16 + 0 + i];
                T1 += gmB[i * 16 + 4 + i];
                T2 += gmB[i * 16 + 8 + i];
                T3 += gmB[i * 16 + 12 + i];
            }
            float t1 = gmB[0 + j * 4 + k] * T0 + gmB[16 + j * 4 + k] * T1
                     + gmB[32 + j * 4 + k] * T2 + gmB[48 + j * 4 + k] * T3;
            float t2 = 0.f;
            #pragma unroll
            for (int m = 0; m < 4; ++m) {
                #pragma unroll
                for (int i = 0; i < 4; ++i)
                    t2 += gmB[m * 16 + j * 4 + i] * gmB[i * 16 + m * 4 + k];
            }
            float t3 = 0.f, t4 = 0.f;
            #pragma unroll
            for (int i = 0; i < 4; ++i) {
                t3 += dgmB[(i * 16 + j * 4 + k) * 4 + i];
                t4 += dgmB[(i * 16 + j * 4 + i) * 4 + k];
            }
            rcB[lane] = t1 - t2 + t3 - t4;
        }
        asm volatile("s_waitcnt lgkmcnt(0)" ::: "memory");

        if (lane < 16) {
            const int j = lane >> 2, k = lane & 3;
            const float R = -rcB[0] + GI1 * rcB[5] + GI2 * rcB[10] + GI3 * rcB[15];
            const float GIj = sel4(j, -1.f, GI1, GI2, GI3);
            const float GIk = sel4(k, -1.f, GI1, GI2, GI3);
            const float o = GIj * GIk * rcB[lane] - ((j == k) ? 0.5f * R * GIj : 0.f);
            out[p * 16 + lane] = o;
        }
        asm volatile("s_waitcnt lgkmcnt(0)" ::: "memory");   // rcB reads retired before next point's z-write
    }
}

extern "C" void kernel_launch(void* const* d_in, const int* in_sizes, int n_in,
                              void* d_out, int out_size, void* d_ws, size_t ws_size,
                              hipStream_t stream) {
    const float* coords = (const float*)d_in[0];
    const float* W1 = (const float*)d_in[1];
    const float* b1 = (const float*)d_in[2];
    const float* W2 = (const float*)d_in[3];
    const float* b2 = (const float*)d_in[4];
    const float* W3 = (const float*)d_in[5];
    const float* b3 = (const float*)d_in[6];
    const float* W4 = (const float*)d_in[7];
    const float* b4 = (const float*)d_in[8];
    const int B = in_sizes[0] / 4;

    hipLaunchKernelGGL(einstein_kernel, dim3(NBLOCKS), dim3(BLOCK), 0, stream,
                       coords, W1, b1, W2, b2, W3, b3, W4, b4,
                       (float*)d_out, B);
}

// Round 7
// 156.929 us; speedup vs baseline: 1.9679x; 1.1540x over previous
//
#include <hip/hip_runtime.h>

#define NBLOCKS 4096
#define WPB 4
#define BLOCK 256

typedef __attribute__((ext_vector_type(8))) short sh8;
typedef __attribute__((ext_vector_type(4))) float f32x4;

__device__ __forceinline__ float sel4(int b, float x0, float x1, float x2, float x3) {
    float r = x3;
    r = (b == 2) ? x2 : r;
    r = (b == 1) ? x1 : r;
    r = (b == 0) ? x0 : r;
    return r;
}

__device__ __forceinline__ float fast_tanh(float x) {
    float e = __expf(2.f * x);
    return 1.f - 2.f / (e + 1.f);
}

// swizzled bf16 index into a [rows][64] LDS array (row stride = 32 dwords).
__device__ __forceinline__ int zidx(int m, int u) {
    return (((m << 5) + (((u >> 1) ^ ((m & 7) << 2)))) << 1) + (u & 1);
}

// load an 8x-bf16 MFMA fragment: row = matrix row, lanes' k-slice = kt*32 + g*8
__device__ __forceinline__ sh8 ldfrag(const unsigned short* base, int row, int g, int kt) {
    const int dw = (row << 5) + ((((kt << 4) + (g << 2))) ^ ((row & 7) << 2));
    return *(const sh8*)(base + (dw << 1));
}

// split f32 into truncated-bf16 hi and bf16(x-hi) lo
__device__ __forceinline__ void wsplit(float x, unsigned short& h, unsigned short& l) {
    const unsigned ub = __float_as_uint(x);
    const unsigned hb = ub & 0xffff0000u;
    const float lf = x - __uint_as_float(hb);
    h = (unsigned short)(hb >> 16);
    l = (unsigned short)(__float_as_uint(lf) >> 16);
}

// launch_bounds(256,3): VGPR cap ~170. (256,5) cap 102 -> catastrophic spill
// (930 MB scratch, R5); (256,4) cap 128 -> partial spill (56 MB scratch, R6).
// Kernel wants ~100-130 VGPR (Whf frags = 64). Occupancy target comes from
// LDS instead: 36 KB/block -> 4 blocks/CU = 50%.
__global__ __launch_bounds__(BLOCK, 3) void einstein_kernel(
    const float* __restrict__ coords,
    const float* __restrict__ gW1, const float* __restrict__ gb1,
    const float* __restrict__ gW2, const float* __restrict__ gb2,
    const float* __restrict__ gW3, const float* __restrict__ gb3,
    const float* __restrict__ gW4, const float* __restrict__ gb4,
    float* __restrict__ out, int B)
{
    // weights transposed+swizzled: [layer][out 64][in 64] bf16 (hi staged first,
    // pulled to regs, then overwritten with lo residual)
    __shared__ __align__(16) unsigned short wlds[2][4096];
    // W4 reduce-GEMM B-fragments: [4 frags][64 lanes][8] bf16 (h0,h1,l0,l1)
    __shared__ __align__(16) unsigned short w4lds[2048];
    // per-wave 4 KB region, time-multiplexed:
    //   phase A: zh = bf16-hi state [0..1023], zl = bf16-lo state [1024..2047]
    //   phase B: cb2 = f32 [64 unit][16] quad-swizzled C transpose (aliases zh/zl)
    //   phase C: red[16] then epilogue gmB/dgmB/rcB/fkB (352 f32, same region)
    __shared__ __align__(16) unsigned short zS[WPB][2048];

    const int wv = threadIdx.x >> 6;
    const int lane = threadIdx.x & 63;
    const int n15 = lane & 15;
    const int g4 = lane >> 4;
    unsigned short* zh = zS[wv];
    unsigned short* zl = zS[wv] + 1024;
    float* cb = (float*)zS[wv];
    float* gmB = cb;          // 64
    float* dgmB = cb + 64;    // 256
    float* rcB = cb + 320;    // 16
    float* fkB = cb + 336;    // 16

    // ---- stage Wh (truncated-bf16) into LDS, pull fragments to registers ----
    for (int e = threadIdx.x; e < 4096; e += BLOCK) {
        const int o = e & 63, i = e >> 6;
        unsigned short h2, l2, h3, l3;
        wsplit(gW2[i * 64 + o], h2, l2);
        wsplit(gW3[i * 64 + o], h3, l3);
        const int ix = zidx(o, i);
        wlds[0][ix] = h2;
        wlds[1][ix] = h3;
    }
    // W4 B-fragments (col 0 = W4, cols 1-15 zero); all waves write identical data
    #pragma unroll
    for (int kt = 0; kt < 2; ++kt) {
        sh8 bh, bl;
        #pragma unroll
        for (int e = 0; e < 8; ++e) {
            const float v = (n15 == 0) ? gW4[kt * 32 + g4 * 8 + e] : 0.f;
            unsigned short h, l;
            wsplit(v, h, l);
            bh[e] = (short)h;
            bl[e] = (short)l;
        }
        *(sh8*)(w4lds + kt * 512 + (lane << 3)) = bh;
        *(sh8*)(w4lds + (2 + kt) * 512 + (lane << 3)) = bl;
    }
    __syncthreads();
    sh8 Whf[2][4][2];
    #pragma unroll
    for (int L = 0; L < 2; ++L)
        #pragma unroll
        for (int nt = 0; nt < 4; ++nt)
            #pragma unroll
            for (int kt = 0; kt < 2; ++kt)
                Whf[L][nt][kt] = ldfrag(wlds[L], nt * 16 + n15, g4, kt);
    __syncthreads();
    // ---- restage with Wl (low bf16 residual) ----
    for (int e = threadIdx.x; e < 4096; e += BLOCK) {
        const int o = e & 63, i = e >> 6;
        unsigned short h2, l2, h3, l3;
        wsplit(gW2[i * 64 + o], h2, l2);
        wsplit(gW3[i * 64 + o], h3, l3);
        const int ix = zidx(o, i);
        wlds[0][ix] = l2;
        wlds[1][ix] = l3;
    }
    __syncthreads();
    // NOTE: A-row 15 (jet 15) is never zeroed; garbage stays confined to C
    // row/col 15 which is never consumed.

    // per-lane layer-1 constants (lane = hidden unit)
    const float w1c0 = gW1[0 * 64 + lane];
    const float w1c1 = gW1[1 * 64 + lane];
    const float w1c2 = gW1[2 * 64 + lane];
    const float w1c3 = gW1[3 * 64 + lane];
    const float b1c = gb1[lane], b2c = gb2[lane], b3c = gb3[lane];
    const float b4v = gb4[0];

    const int wid = blockIdx.x * WPB + wv;
    const int nw = NBLOCKS * WPB;

    for (int p = wid; p < B; p += nw) {
        const float4 c4 = reinterpret_cast<const float4*>(coords)[p];
        const float cr = c4.y, cth = c4.z;

        float z[15];
        // ---------- layer 1 (4 -> 64), closed-form jet, lane = unit
        {
            const float u = b1c + c4.x * w1c0 + cr * w1c1 + cth * w1c2 + c4.w * w1c3;
            const float y = fast_tanh(u);
            const float D = 1.f - y * y;
            const float m2 = -2.f * y * D;
            z[0] = y;
            z[1] = D * w1c0; z[2] = D * w1c1; z[3] = D * w1c2; z[4] = D * w1c3;
            z[5] = m2 * w1c0 * w1c0; z[6] = m2 * w1c0 * w1c1; z[7] = m2 * w1c0 * w1c2; z[8] = m2 * w1c0 * w1c3;
            z[9] = m2 * w1c1 * w1c1; z[10] = m2 * w1c1 * w1c2; z[11] = m2 * w1c1 * w1c3;
            z[12] = m2 * w1c2 * w1c2; z[13] = m2 * w1c2 * w1c3; z[14] = m2 * w1c3 * w1c3;
        }
        #pragma unroll
        for (int m = 0; m < 15; ++m) {
            unsigned short h, l;
            wsplit(z[m], h, l);
            const int ix = zidx(m, lane);
            zh[ix] = h;
            zl[ix] = l;
        }
        asm volatile("s_waitcnt lgkmcnt(0)" ::: "memory");

        // ---------- layers 2,3: jet-GEMM on MFMA with hi/lo split
        #pragma unroll
        for (int LL = 0; LL < 2; ++LL) {
            const unsigned short* wl = wlds[LL];
            const sh8 Ah0 = ldfrag(zh, n15, g4, 0);
            const sh8 Ah1 = ldfrag(zh, n15, g4, 1);
            const sh8 Al0 = ldfrag(zl, n15, g4, 0);
            const sh8 Al1 = ldfrag(zl, n15, g4, 1);
            f32x4 acc[4];
            #pragma unroll
            for (int nt = 0; nt < 4; ++nt) {
                f32x4 a0 = {0.f, 0.f, 0.f, 0.f};
                const sh8 Bl0 = ldfrag(wl, nt * 16 + n15, g4, 0);
                const sh8 Bl1 = ldfrag(wl, nt * 16 + n15, g4, 1);
                a0 = __builtin_amdgcn_mfma_f32_16x16x32_bf16(Ah0, Whf[LL][nt][0], a0, 0, 0, 0);
                a0 = __builtin_amdgcn_mfma_f32_16x16x32_bf16(Ah1, Whf[LL][nt][1], a0, 0, 0, 0);
                a0 = __builtin_amdgcn_mfma_f32_16x16x32_bf16(Al0, Whf[LL][nt][0], a0, 0, 0, 0);
                a0 = __builtin_amdgcn_mfma_f32_16x16x32_bf16(Al1, Whf[LL][nt][1], a0, 0, 0, 0);
                a0 = __builtin_amdgcn_mfma_f32_16x16x32_bf16(Ah0, Bl0, a0, 0, 0, 0);
                a0 = __builtin_amdgcn_mfma_f32_16x16x32_bf16(Ah1, Bl1, a0, 0, 0, 0);
                acc[nt] = a0;
            }
            // vectorized transpose through cb2[u][16] (aliases zh/zl; A-frags in
            // regs). Quad-XOR swizzle: phys_quad = log_quad ^ (u&12) -> b128
            // scatter AND gather both at the 32-bank floor.
            asm volatile("s_waitcnt lgkmcnt(0)" ::: "memory");
            #pragma unroll
            for (int nt = 0; nt < 4; ++nt) {
                const int u = nt * 16 + n15;
                *(f32x4*)(cb + u * 16 + ((g4 << 2) ^ (u & 12))) = acc[nt];
            }
            asm volatile("s_waitcnt lgkmcnt(0)" ::: "memory");
            float a[15];
            #pragma unroll
            for (int c = 0; c < 4; ++c) {
                const f32x4 r = *(const f32x4*)(cb + lane * 16 + ((c << 2) ^ (lane & 12)));
                #pragma unroll
                for (int t = 0; t < 4; ++t)
                    if (c * 4 + t < 15) a[c * 4 + t] = r[t];
            }
            asm volatile("s_waitcnt lgkmcnt(0)" ::: "memory");   // gather retired before z-write clobbers

            const float a0v = a[0] + (LL ? b3c : b2c);
            const float y = fast_tanh(a0v);
            const float D = 1.f - y * y;
            const float m2 = -2.f * y * D;
            z[0] = y;
            z[1] = D * a[1]; z[2] = D * a[2]; z[3] = D * a[3]; z[4] = D * a[4];
            z[5] = D * a[5] + m2 * a[1] * a[1];
            z[6] = D * a[6] + m2 * a[1] * a[2];
            z[7] = D * a[7] + m2 * a[1] * a[3];
            z[8] = D * a[8] + m2 * a[1] * a[4];
            z[9] = D * a[9] + m2 * a[2] * a[2];
            z[10] = D * a[10] + m2 * a[2] * a[3];
            z[11] = D * a[11] + m2 * a[2] * a[4];
            z[12] = D * a[12] + m2 * a[3] * a[3];
            z[13] = D * a[13] + m2 * a[3] * a[4];
            z[14] = D * a[14] + m2 * a[4] * a[4];

            // stage z for next layer (LL=0) or for the reduce-GEMM (LL=1)
            #pragma unroll
            for (int m = 0; m < 15; ++m) {
                unsigned short h, l;
                wsplit(z[m], h, l);
                const int ix = zidx(m, lane);
                zh[ix] = h;
                zl[ix] = l;
            }
            asm volatile("s_waitcnt lgkmcnt(0)" ::: "memory");
        }

        // ---------- final layer (64 -> 1) as MFMA reduce: C[m][0] = sum_u z[m][u]*w4[u]
        {
            const sh8 Ah0 = ldfrag(zh, n15, g4, 0);
            const sh8 Ah1 = ldfrag(zh, n15, g4, 1);
            const sh8 Al0 = ldfrag(zl, n15, g4, 0);
            const sh8 Al1 = ldfrag(zl, n15, g4, 1);
            const sh8 Bh0 = *(const sh8*)(w4lds + 0 * 512 + (lane << 3));
            const sh8 Bh1 = *(const sh8*)(w4lds + 1 * 512 + (lane << 3));
            const sh8 Bl0 = *(const sh8*)(w4lds + 2 * 512 + (lane << 3));
            const sh8 Bl1 = *(const sh8*)(w4lds + 3 * 512 + (lane << 3));
            asm volatile("s_waitcnt lgkmcnt(0)" ::: "memory");
            f32x4 rs = {0.f, 0.f, 0.f, 0.f};
            rs = __builtin_amdgcn_mfma_f32_16x16x32_bf16(Ah0, Bh0, rs, 0, 0, 0);
            rs = __builtin_amdgcn_mfma_f32_16x16x32_bf16(Ah1, Bh1, rs, 0, 0, 0);
            rs = __builtin_amdgcn_mfma_f32_16x16x32_bf16(Al0, Bh0, rs, 0, 0, 0);
            rs = __builtin_amdgcn_mfma_f32_16x16x32_bf16(Al1, Bh1, rs, 0, 0, 0);
            rs = __builtin_amdgcn_mfma_f32_16x16x32_bf16(Ah0, Bl0, rs, 0, 0, 0);
            rs = __builtin_amdgcn_mfma_f32_16x16x32_bf16(Ah1, Bl1, rs, 0, 0, 0);
            // sums live in col 0 = lanes {0,16,32,48}, row m = g4*4+j
            if (n15 == 0) *(f32x4*)(cb + (g4 << 2)) = rs;
        }
        asm volatile("s_waitcnt lgkmcnt(0)" ::: "memory");
        const f32x4 r0 = *(const f32x4*)(cb);        // m 0-3
        const f32x4 r1 = *(const f32x4*)(cb + 4);    // m 4-7
        const f32x4 r2 = *(const f32x4*)(cb + 8);    // m 8-11
        const f32x4 r3 = *(const f32x4*)(cb + 12);   // m 12-14
        asm volatile("s_waitcnt lgkmcnt(0)" ::: "memory");   // reads retired before epilogue overwrites cb
        const float f = r0[0] + b4v;
        const float fj0 = r0[1], fj1 = r0[2], fj2 = r0[3], fj3 = r1[0];
        const float s00 = r1[1], s01 = r1[2], s02 = r1[3];
        const float s03 = r2[0], s11 = r2[1], s12 = r2[2], s13 = r2[3];
        const float s22 = r3[0], s23 = r3[1], s33 = r3[2];

        // ---------- analytic Einstein tensor
        float S, Cq;
        __sincosf(cth, &S, &Cq);
        const float E = __expf(f);
        const float r2v = cr * cr, S2 = S * S;
        const float GI1 = 1.f / E;
        const float GI2 = 1.f / r2v;
        const float GI3 = GI2 / S2;
        const float d3_r = 2.f * cr * S2;
        const float d3_th = 2.f * r2v * S * Cq;
        const float dd_rr = 2.f * S2;
        const float dd_rth = 4.f * cr * S * Cq;
        const float dd_thth = 2.f * r2v * (Cq * Cq - S2);

        if (lane < 16) {
            const int jj = lane >> 2, kk = lane & 3;
            const int lo = jj < kk ? jj : kk, hi = jj < kk ? kk : jj;
            const int code = lo * 4 + hi;
            float v = s33;
            v = code == 0 ? s00 : v;  v = code == 1 ? s01 : v;  v = code == 2 ? s02 : v;
            v = code == 3 ? s03 : v;  v = code == 5 ? s11 : v;  v = code == 6 ? s12 : v;
            v = code == 7 ? s13 : v;  v = code == 10 ? s22 : v; v = code == 11 ? s23 : v;
            fkB[lane] = v;
        }
        asm volatile("s_waitcnt lgkmcnt(0)" ::: "memory");

        auto fjsel = [&](int b) { return sel4(b, fj0, fj1, fj2, fj3); };
        auto dgd = [&](int a, int b) {
            float v1 = E * fjsel(b);
            float v2 = (b == 1) ? (2.f * cr) : 0.f;
            float v3 = (b == 1) ? d3_r : ((b == 2) ? d3_th : 0.f);
            return (a == 1) ? v1 : ((a == 2) ? v2 : ((a == 3) ? v3 : 0.f));
        };
        auto d2f = [&](int a, int b, int l) {
            float v1 = E * (fjsel(b) * fjsel(l) + fkB[b * 4 + l]);
            float v2 = (b == 1 && l == 1) ? 2.f : 0.f;
            float v3 = (b == 1 && l == 1) ? dd_rr
                       : (((b == 1 && l == 2) || (b == 2 && l == 1)) ? dd_rth
                       : ((b == 2 && l == 2) ? dd_thth : 0.f));
            return (a == 1) ? v1 : ((a == 2) ? v2 : ((a == 3) ? v3 : 0.f));
        };

        const int li = (lane >> 4) & 3, lk = (lane >> 2) & 3, lj = lane & 3;
        const float GIi = sel4(li, -1.f, GI1, GI2, GI3);
        float P = (lk == li ? dgd(li, lj) : 0.f)
                + (lj == li ? dgd(li, lk) : 0.f)
                - (lj == lk ? dgd(lj, li) : 0.f);
        gmB[lane] = 0.5f * GIi * P;
        const float GIi2 = GIi * GIi;
        float dgm0, dgm1, dgm2, dgm3;
        {
            float Q0 = (lk == li ? d2f(li, lj, 0) : 0.f) + (lj == li ? d2f(li, lk, 0) : 0.f) - (lj == lk ? d2f(lj, li, 0) : 0.f);
            float Q1 = (lk == li ? d2f(li, lj, 1) : 0.f) + (lj == li ? d2f(li, lk, 1) : 0.f) - (lj == lk ? d2f(lj, li, 1) : 0.f);
            float Q2 = (lk == li ? d2f(li, lj, 2) : 0.f) + (lj == li ? d2f(li, lk, 2) : 0.f) - (lj == lk ? d2f(lj, li, 2) : 0.f);
            float Q3 = (lk == li ? d2f(li, lj, 3) : 0.f) + (lj == li ? d2f(li, lk, 3) : 0.f) - (lj == lk ? d2f(lj, li, 3) : 0.f);
            dgm0 = 0.5f * (GIi * Q0 - dgd(li, 0) * GIi2 * P);
            dgm1 = 0.5f * (GIi * Q1 - dgd(li, 1) * GIi2 * P);
            dgm2 = 0.5f * (GIi * Q2 - dgd(li, 2) * GIi2 * P);
            dgm3 = 0.5f * (GIi * Q3 - dgd(li, 3) * GIi2 * P);
        }
        reinterpret_cast<float4*>(dgmB)[lane] = make_float4(dgm0, dgm1, dgm2, dgm3);
        asm volatile("s_waitcnt lgkmcnt(0)" ::: "memory");

        if (lane < 16) {
            const int j = lane >> 2, k = lane & 3;
            float T0 = 0, T1 = 0, T2 = 0, T3 = 0;
            #pragma unroll
            for (int i = 0; i < 4; ++i) {
                T0 += gmB[i * 16 + 0 + i];
                T1 += gmB[i * 16 + 4 + i];
                T2 += gmB[i * 16 + 8 + i];
                T3 += gmB[i * 16 + 12 + i];
            }
            float t1 = gmB[0 + j * 4 + k] * T0 + gmB[16 + j * 4 + k] * T1
                     + gmB[32 + j * 4 + k] * T2 + gmB[48 + j * 4 + k] * T3;
            float t2 = 0.f;
            #pragma unroll
            for (int m = 0; m < 4; ++m) {
                #pragma unroll
                for (int i = 0; i < 4; ++i)
                    t2 += gmB[m * 16 + j * 4 + i] * gmB[i * 16 + m * 4 + k];
            }
            float t3 = 0.f, t4 = 0.f;
            #pragma unroll
            for (int i = 0; i < 4; ++i) {
                t3 += dgmB[(i * 16 + j * 4 + k) * 4 + i];
                t4 += dgmB[(i * 16 + j * 4 + i) * 4 + k];
            }
            rcB[lane] = t1 - t2 + t3 - t4;
        }
        asm volatile("s_waitcnt lgkmcnt(0)" ::: "memory");

        if (lane < 16) {
            const int j = lane >> 2, k = lane & 3;
            const float R = -rcB[0] + GI1 * rcB[5] + GI2 * rcB[10] + GI3 * rcB[15];
            const float GIj = sel4(j, -1.f, GI1, GI2, GI3);
            const float GIk = sel4(k, -1.f, GI1, GI2, GI3);
            const float o = GIj * GIk * rcB[lane] - ((j == k) ? 0.5f * R * GIj : 0.f);
            out[p * 16 + lane] = o;
        }
        asm volatile("s_waitcnt lgkmcnt(0)" ::: "memory");   // rcB reads retired before next point's z-write
    }
}

extern "C" void kernel_launch(void* const* d_in, const int* in_sizes, int n_in,
                              void* d_out, int out_size, void* d_ws, size_t ws_size,
                              hipStream_t stream) {
    const float* coords = (const float*)d_in[0];
    const float* W1 = (const float*)d_in[1];
    const float* b1 = (const float*)d_in[2];
    const float* W2 = (const float*)d_in[3];
    const float* b2 = (const float*)d_in[4];
    const float* W3 = (const float*)d_in[5];
    const float* b3 = (const float*)d_in[6];
    const float* W4 = (const float*)d_in[7];
    const float* b4 = (const float*)d_in[8];
    const int B = in_sizes[0] / 4;

    hipLaunchKernelGGL(einstein_kernel, dim3(NBLOCKS), dim3(BLOCK), 0, stream,
                       coords, W1, b1, W2, b2, W3, b3, W4, b4,
                       (float*)d_out, B);
}

// Round 8
// 155.734 us; speedup vs baseline: 1.9830x; 1.0077x over previous
//
#include <hip/hip_runtime.h>

#define NBLOCKS 4096
#define WPB 4
#define BLOCK 256

typedef __attribute__((ext_vector_type(8))) short sh8;
typedef __attribute__((ext_vector_type(4))) float f32x4;

__device__ __forceinline__ float sel4(int b, float x0, float x1, float x2, float x3) {
    float r = x3;
    r = (b == 2) ? x2 : r;
    r = (b == 1) ? x1 : r;
    r = (b == 0) ? x0 : r;
    return r;
}

__device__ __forceinline__ float fast_tanh(float x) {
    float e = __expf(2.f * x);
    return 1.f - 2.f / (e + 1.f);
}

// swizzled bf16 index into a [rows][64] LDS array (row stride = 32 dwords).
__device__ __forceinline__ int zidx(int m, int u) {
    return (((m << 5) + (((u >> 1) ^ ((m & 7) << 2)))) << 1) + (u & 1);
}

// load an 8x-bf16 MFMA fragment: row = matrix row, lanes' k-slice = kt*32 + g*8
__device__ __forceinline__ sh8 ldfrag(const unsigned short* base, int row, int g, int kt) {
    const int dw = (row << 5) + ((((kt << 4) + (g << 2))) ^ ((row & 7) << 2));
    return *(const sh8*)(base + (dw << 1));
}

// split f32 into truncated-bf16 hi and bf16(x-hi) lo
__device__ __forceinline__ void wsplit(float x, unsigned short& h, unsigned short& l) {
    const unsigned ub = __float_as_uint(x);
    const unsigned hb = ub & 0xffff0000u;
    const float lf = x - __uint_as_float(hb);
    h = (unsigned short)(hb >> 16);
    l = (unsigned short)(__float_as_uint(lf) >> 16);
}

__device__ __forceinline__ void stage15(unsigned short* zh, unsigned short* zl,
                                        const float* z, int lane) {
    #pragma unroll
    for (int m = 0; m < 15; ++m) {
        unsigned short h, l;
        wsplit(z[m], h, l);
        const int ix = zidx(m, lane);
        zh[ix] = h;
        zl[ix] = l;
    }
}

__device__ __forceinline__ void jet_nl(const float* a, float bias, float* z) {
    const float a0v = a[0] + bias;
    const float y = fast_tanh(a0v);
    const float D = 1.f - y * y;
    const float m2 = -2.f * y * D;
    z[0] = y;
    z[1] = D * a[1]; z[2] = D * a[2]; z[3] = D * a[3]; z[4] = D * a[4];
    z[5] = D * a[5] + m2 * a[1] * a[1];
    z[6] = D * a[6] + m2 * a[1] * a[2];
    z[7] = D * a[7] + m2 * a[1] * a[3];
    z[8] = D * a[8] + m2 * a[1] * a[4];
    z[9] = D * a[9] + m2 * a[2] * a[2];
    z[10] = D * a[10] + m2 * a[2] * a[3];
    z[11] = D * a[11] + m2 * a[2] * a[4];
    z[12] = D * a[12] + m2 * a[3] * a[3];
    z[13] = D * a[13] + m2 * a[3] * a[4];
    z[14] = D * a[14] + m2 * a[4] * a[4];
}

#define WAITLDS asm volatile("s_waitcnt lgkmcnt(0)" ::: "memory")

// launch_bounds(256,3): VGPR cap ~170. (256,5) cap 102 -> catastrophic spill
// (930 MB scratch, R5); (256,4) cap 128 -> partial spill (56 MB scratch, R6).
// 2-pt version needs ~120-140 VGPR (Whf frags 64 + 2x A-frags 32). Watch
// WRITE_SIZE: >10 MB means spill returned.
__global__ __launch_bounds__(BLOCK, 3) void einstein_kernel(
    const float* __restrict__ coords,
    const float* __restrict__ gW1, const float* __restrict__ gb1,
    const float* __restrict__ gW2, const float* __restrict__ gb2,
    const float* __restrict__ gW3, const float* __restrict__ gb3,
    const float* __restrict__ gW4, const float* __restrict__ gb4,
    float* __restrict__ out, int B)
{
    // weights transposed+swizzled: [layer][out 64][in 64] bf16 (hi staged first,
    // pulled to regs, then overwritten with lo residual)
    __shared__ __align__(16) unsigned short wlds[2][4096];
    // W4 reduce-GEMM B-fragments: [4 frags][64 lanes][8] bf16 (h0,h1,l0,l1)
    __shared__ __align__(16) unsigned short w4lds[2048];
    // per-wave 8 KB, 2 points x 4 KB; each 4 KB time-multiplexed:
    //   phase A: zh [0..1023] + zl [1024..2047] (bf16 jet state)
    //   phase B: cb = f32 [64][16] quad-swizzled C transpose (aliases zh/zl)
    //   phase C: reduce row + epilogue gmB/dgmB/rcB/fkB (352 f32, same region)
    __shared__ __align__(16) unsigned short zS[WPB][4096];

    const int wv = threadIdx.x >> 6;
    const int lane = threadIdx.x & 63;
    const int n15 = lane & 15;
    const int g4 = lane >> 6 ? 0 : (lane >> 4); // (lane>>4), kept simple below
    const int g = lane >> 4;

    unsigned short* zbase = zS[wv];

    // ---- stage Wh (truncated-bf16) into LDS, pull fragments to registers ----
    for (int e = threadIdx.x; e < 4096; e += BLOCK) {
        const int o = e & 63, i = e >> 6;
        unsigned short h2, l2, h3, l3;
        wsplit(gW2[i * 64 + o], h2, l2);
        wsplit(gW3[i * 64 + o], h3, l3);
        const int ix = zidx(o, i);
        wlds[0][ix] = h2;
        wlds[1][ix] = h3;
    }
    // W4 B-fragments (col 0 = W4, cols 1-15 zero); all waves write identical data
    #pragma unroll
    for (int kt = 0; kt < 2; ++kt) {
        sh8 bh, bl;
        #pragma unroll
        for (int e = 0; e < 8; ++e) {
            const float v = (n15 == 0) ? gW4[kt * 32 + g * 8 + e] : 0.f;
            unsigned short h, l;
            wsplit(v, h, l);
            bh[e] = (short)h;
            bl[e] = (short)l;
        }
        *(sh8*)(w4lds + kt * 512 + (lane << 3)) = bh;
        *(sh8*)(w4lds + (2 + kt) * 512 + (lane << 3)) = bl;
    }
    __syncthreads();
    sh8 Whf[2][4][2];
    #pragma unroll
    for (int L = 0; L < 2; ++L)
        #pragma unroll
        for (int nt = 0; nt < 4; ++nt)
            #pragma unroll
            for (int kt = 0; kt < 2; ++kt)
                Whf[L][nt][kt] = ldfrag(wlds[L], nt * 16 + n15, g, kt);
    __syncthreads();
    // ---- restage with Wl (low bf16 residual) ----
    for (int e = threadIdx.x; e < 4096; e += BLOCK) {
        const int o = e & 63, i = e >> 6;
        unsigned short h2, l2, h3, l3;
        wsplit(gW2[i * 64 + o], h2, l2);
        wsplit(gW3[i * 64 + o], h3, l3);
        const int ix = zidx(o, i);
        wlds[0][ix] = l2;
        wlds[1][ix] = l3;
    }
    __syncthreads();
    // A-row 15 (jet 15) never zeroed; garbage confined to C row/col 15, unread.

    // per-lane layer-1 constants (lane = hidden unit)
    const float w1c0 = gW1[0 * 64 + lane];
    const float w1c1 = gW1[1 * 64 + lane];
    const float w1c2 = gW1[2 * 64 + lane];
    const float w1c3 = gW1[3 * 64 + lane];
    const float b1c = gb1[lane], b2c = gb2[lane], b3c = gb3[lane];
    const float b4v = gb4[0];

    const int wid = blockIdx.x * WPB + wv;
    const int nw = NBLOCKS * WPB;

    for (int p = 2 * wid; p < B; p += 2 * nw) {
        float4 c4[2];
        c4[0] = reinterpret_cast<const float4*>(coords)[p];
        c4[1] = reinterpret_cast<const float4*>(coords)[p + 1];

        float z[2][15];
        // ---------- layer 1 (4 -> 64), closed-form jet, lane = unit; both points
        #pragma unroll
        for (int pt = 0; pt < 2; ++pt) {
            const float u = b1c + c4[pt].x * w1c0 + c4[pt].y * w1c1 + c4[pt].z * w1c2 + c4[pt].w * w1c3;
            const float y = fast_tanh(u);
            const float D = 1.f - y * y;
            const float m2 = -2.f * y * D;
            z[pt][0] = y;
            z[pt][1] = D * w1c0; z[pt][2] = D * w1c1; z[pt][3] = D * w1c2; z[pt][4] = D * w1c3;
            z[pt][5] = m2 * w1c0 * w1c0; z[pt][6] = m2 * w1c0 * w1c1; z[pt][7] = m2 * w1c0 * w1c2; z[pt][8] = m2 * w1c0 * w1c3;
            z[pt][9] = m2 * w1c1 * w1c1; z[pt][10] = m2 * w1c1 * w1c2; z[pt][11] = m2 * w1c1 * w1c3;
            z[pt][12] = m2 * w1c2 * w1c2; z[pt][13] = m2 * w1c2 * w1c3; z[pt][14] = m2 * w1c3 * w1c3;
            stage15(zbase + pt * 2048, zbase + pt * 2048 + 1024, z[pt], lane);
        }
        WAITLDS;

        // ---------- layers 2,3: jet-GEMM on MFMA with hi/lo split, 2 pts interleaved
        #pragma unroll
        for (int LL = 0; LL < 2; ++LL) {
            const unsigned short* wl = wlds[LL];
            sh8 Ah0[2], Ah1[2], Al0[2], Al1[2];
            #pragma unroll
            for (int pt = 0; pt < 2; ++pt) {
                unsigned short* zh = zbase + pt * 2048;
                unsigned short* zl = zh + 1024;
                Ah0[pt] = ldfrag(zh, n15, g, 0);
                Ah1[pt] = ldfrag(zh, n15, g, 1);
                Al0[pt] = ldfrag(zl, n15, g, 0);
                Al1[pt] = ldfrag(zl, n15, g, 1);
            }
            WAITLDS;   // frag reads retired before scatter clobbers the alias
            #pragma unroll
            for (int nt = 0; nt < 4; ++nt) {
                const sh8 Bl0 = ldfrag(wl, nt * 16 + n15, g, 0);
                const sh8 Bl1 = ldfrag(wl, nt * 16 + n15, g, 1);
                #pragma unroll
                for (int pt = 0; pt < 2; ++pt) {
                    f32x4 a0 = {0.f, 0.f, 0.f, 0.f};
                    a0 = __builtin_amdgcn_mfma_f32_16x16x32_bf16(Ah0[pt], Whf[LL][nt][0], a0, 0, 0, 0);
                    a0 = __builtin_amdgcn_mfma_f32_16x16x32_bf16(Ah1[pt], Whf[LL][nt][1], a0, 0, 0, 0);
                    a0 = __builtin_amdgcn_mfma_f32_16x16x32_bf16(Al0[pt], Whf[LL][nt][0], a0, 0, 0, 0);
                    a0 = __builtin_amdgcn_mfma_f32_16x16x32_bf16(Al1[pt], Whf[LL][nt][1], a0, 0, 0, 0);
                    a0 = __builtin_amdgcn_mfma_f32_16x16x32_bf16(Ah0[pt], Bl0, a0, 0, 0, 0);
                    a0 = __builtin_amdgcn_mfma_f32_16x16x32_bf16(Ah1[pt], Bl1, a0, 0, 0, 0);
                    float* cb = (float*)zbase + pt * 1024;
                    const int u = nt * 16 + n15;
                    *(f32x4*)(cb + u * 16 + ((g << 2) ^ (u & 12))) = a0;
                }
            }
            WAITLDS;   // scatters visible
            float a[2][15];
            #pragma unroll
            for (int pt = 0; pt < 2; ++pt) {
                float* cb = (float*)zbase + pt * 1024;
                #pragma unroll
                for (int c = 0; c < 4; ++c) {
                    const f32x4 r = *(const f32x4*)(cb + lane * 16 + ((c << 2) ^ (lane & 12)));
                    #pragma unroll
                    for (int t = 0; t < 4; ++t)
                        if (c * 4 + t < 15) a[pt][c * 4 + t] = r[t];
                }
            }
            WAITLDS;   // gathers retired before restage clobbers
            #pragma unroll
            for (int pt = 0; pt < 2; ++pt) {
                jet_nl(a[pt], LL ? b3c : b2c, z[pt]);
                stage15(zbase + pt * 2048, zbase + pt * 2048 + 1024, z[pt], lane);
            }
            WAITLDS;
        }

        // ---------- final layer (64 -> 1) as MFMA reduce, shared W4 B-frags
        {
            const sh8 Bh0 = *(const sh8*)(w4lds + 0 * 512 + (lane << 3));
            const sh8 Bh1 = *(const sh8*)(w4lds + 1 * 512 + (lane << 3));
            const sh8 Bw0 = *(const sh8*)(w4lds + 2 * 512 + (lane << 3));
            const sh8 Bw1 = *(const sh8*)(w4lds + 3 * 512 + (lane << 3));
            f32x4 rs[2];
            #pragma unroll
            for (int pt = 0; pt < 2; ++pt) {
                unsigned short* zh = zbase + pt * 2048;
                unsigned short* zl = zh + 1024;
                const sh8 Ah0 = ldfrag(zh, n15, g, 0);
                const sh8 Ah1 = ldfrag(zh, n15, g, 1);
                const sh8 Al0 = ldfrag(zl, n15, g, 0);
                const sh8 Al1 = ldfrag(zl, n15, g, 1);
                f32x4 r = {0.f, 0.f, 0.f, 0.f};
                r = __builtin_amdgcn_mfma_f32_16x16x32_bf16(Ah0, Bh0, r, 0, 0, 0);
                r = __builtin_amdgcn_mfma_f32_16x16x32_bf16(Ah1, Bh1, r, 0, 0, 0);
                r = __builtin_amdgcn_mfma_f32_16x16x32_bf16(Al0, Bh0, r, 0, 0, 0);
                r = __builtin_amdgcn_mfma_f32_16x16x32_bf16(Al1, Bh1, r, 0, 0, 0);
                r = __builtin_amdgcn_mfma_f32_16x16x32_bf16(Ah0, Bw0, r, 0, 0, 0);
                r = __builtin_amdgcn_mfma_f32_16x16x32_bf16(Ah1, Bw1, r, 0, 0, 0);
                rs[pt] = r;
            }
            WAITLDS;   // frag reads retired before col-0 write clobbers zh row 0
            if (n15 == 0) {
                *(f32x4*)((float*)zbase + (g << 2)) = rs[0];
                *(f32x4*)((float*)zbase + 1024 + (g << 2)) = rs[1];
            }
        }
        WAITLDS;
        float fv[2], fja[2][4], sv[2][10];
        #pragma unroll
        for (int pt = 0; pt < 2; ++pt) {
            const float* cb = (const float*)zbase + pt * 1024;
            const f32x4 r0 = *(const f32x4*)(cb);
            const f32x4 r1 = *(const f32x4*)(cb + 4);
            const f32x4 r2 = *(const f32x4*)(cb + 8);
            const f32x4 r3 = *(const f32x4*)(cb + 12);
            fv[pt] = r0[0] + b4v;
            fja[pt][0] = r0[1]; fja[pt][1] = r0[2]; fja[pt][2] = r0[3]; fja[pt][3] = r1[0];
            sv[pt][0] = r1[1]; sv[pt][1] = r1[2]; sv[pt][2] = r1[3];
            sv[pt][3] = r2[0]; sv[pt][4] = r2[1]; sv[pt][5] = r2[2]; sv[pt][6] = r2[3];
            sv[pt][7] = r3[0]; sv[pt][8] = r3[1]; sv[pt][9] = r3[2];
        }
        WAITLDS;   // reduce reads retired before epilogue overwrites cb

        // ---------- analytic Einstein tensor, 2 pts phase-merged
        // stage Hessian of f (4x4) for runtime-index access
        #pragma unroll
        for (int pt = 0; pt < 2; ++pt) {
            if (lane < 16) {
                float* fkB = (float*)zbase + pt * 1024 + 336;
                const int jj = lane >> 2, kk = lane & 3;
                const int lo = jj < kk ? jj : kk, hi = jj < kk ? kk : jj;
                const int code = lo * 4 + hi;
                float v = sv[pt][9];
                v = code == 0 ? sv[pt][0] : v;  v = code == 1 ? sv[pt][1] : v;  v = code == 2 ? sv[pt][2] : v;
                v = code == 3 ? sv[pt][3] : v;  v = code == 5 ? sv[pt][4] : v;  v = code == 6 ? sv[pt][5] : v;
                v = code == 7 ? sv[pt][6] : v;  v = code == 10 ? sv[pt][7] : v; v = code == 11 ? sv[pt][8] : v;
                fkB[lane] = v;
            }
        }
        WAITLDS;

        const int li = (lane >> 4) & 3, lk = (lane >> 2) & 3, lj = lane & 3;
        #pragma unroll
        for (int pt = 0; pt < 2; ++pt) {
            float* cb = (float*)zbase + pt * 1024;
            float* gmB = cb;
            float* dgmB = cb + 64;
            const float* fkB = cb + 336;
            const float cr = c4[pt].y, cth = c4[pt].z;
            float S, Cq;
            __sincosf(cth, &S, &Cq);
            const float E = __expf(fv[pt]);
            const float r2v = cr * cr, S2 = S * S;
            const float GI1 = 1.f / E;
            const float GI2 = 1.f / r2v;
            const float GI3 = GI2 / S2;
            const float d3_r = 2.f * cr * S2;
            const float d3_th = 2.f * r2v * S * Cq;
            const float dd_rr = 2.f * S2;
            const float dd_rth = 4.f * cr * S * Cq;
            const float dd_thth = 2.f * r2v * (Cq * Cq - S2);

            auto fjsel = [&](int b) { return sel4(b, fja[pt][0], fja[pt][1], fja[pt][2], fja[pt][3]); };
            auto dgd = [&](int a, int b) {
                float v1 = E * fjsel(b);
                float v2 = (b == 1) ? (2.f * cr) : 0.f;
                float v3 = (b == 1) ? d3_r : ((b == 2) ? d3_th : 0.f);
                return (a == 1) ? v1 : ((a == 2) ? v2 : ((a == 3) ? v3 : 0.f));
            };
            auto d2f = [&](int a, int b, int l) {
                float v1 = E * (fjsel(b) * fjsel(l) + fkB[b * 4 + l]);
                float v2 = (b == 1 && l == 1) ? 2.f : 0.f;
                float v3 = (b == 1 && l == 1) ? dd_rr
                           : (((b == 1 && l == 2) || (b == 2 && l == 1)) ? dd_rth
                           : ((b == 2 && l == 2) ? dd_thth : 0.f));
                return (a == 1) ? v1 : ((a == 2) ? v2 : ((a == 3) ? v3 : 0.f));
            };

            const float GIi = sel4(li, -1.f, GI1, GI2, GI3);
            float P = (lk == li ? dgd(li, lj) : 0.f)
                    + (lj == li ? dgd(li, lk) : 0.f)
                    - (lj == lk ? dgd(lj, li) : 0.f);
            gmB[lane] = 0.5f * GIi * P;
            const float GIi2 = GIi * GIi;
            float Q0 = (lk == li ? d2f(li, lj, 0) : 0.f) + (lj == li ? d2f(li, lk, 0) : 0.f) - (lj == lk ? d2f(lj, li, 0) : 0.f);
            float Q1 = (lk == li ? d2f(li, lj, 1) : 0.f) + (lj == li ? d2f(li, lk, 1) : 0.f) - (lj == lk ? d2f(lj, li, 1) : 0.f);
            float Q2 = (lk == li ? d2f(li, lj, 2) : 0.f) + (lj == li ? d2f(li, lk, 2) : 0.f) - (lj == lk ? d2f(lj, li, 2) : 0.f);
            float Q3 = (lk == li ? d2f(li, lj, 3) : 0.f) + (lj == li ? d2f(li, lk, 3) : 0.f) - (lj == lk ? d2f(lj, li, 3) : 0.f);
            const float dgm0 = 0.5f * (GIi * Q0 - dgd(li, 0) * GIi2 * P);
            const float dgm1 = 0.5f * (GIi * Q1 - dgd(li, 1) * GIi2 * P);
            const float dgm2 = 0.5f * (GIi * Q2 - dgd(li, 2) * GIi2 * P);
            const float dgm3 = 0.5f * (GIi * Q3 - dgd(li, 3) * GIi2 * P);
            reinterpret_cast<float4*>(dgmB)[lane] = make_float4(dgm0, dgm1, dgm2, dgm3);
        }
        WAITLDS;

        #pragma unroll
        for (int pt = 0; pt < 2; ++pt) {
            if (lane < 16) {
                float* cb = (float*)zbase + pt * 1024;
                const float* gmB = cb;
                const float* dgmB = cb + 64;
                float* rcB = cb + 320;
                const int j = lane >> 2, k = lane & 3;
                float T0 = 0, T1 = 0, T2 = 0, T3 = 0;
                #pragma unroll
                for (int i = 0; i < 4; ++i) {
                    T0 += gmB[i * 16 + 0 + i];
                    T1 += gmB[i * 16 + 4 + i];
                    T2 += gmB[i * 16 + 8 + i];
                    T3 += gmB[i * 16 + 12 + i];
                }
                float t1 = gmB[0 + j * 4 + k] * T0 + gmB[16 + j * 4 + k] * T1
                         + gmB[32 + j * 4 + k] * T2 + gmB[48 + j * 4 + k] * T3;
                float t2 = 0.f;
                #pragma unroll
                for (int m = 0; m < 4; ++m)
                    #pragma unroll
                    for (int i = 0; i < 4; ++i)
                        t2 += gmB[m * 16 + j * 4 + i] * gmB[i * 16 + m * 4 + k];
                float t3 = 0.f, t4 = 0.f;
                #pragma unroll
                for (int i = 0; i < 4; ++i) {
                    t3 += dgmB[(i * 16 + j * 4 + k) * 4 + i];
                    t4 += dgmB[(i * 16 + j * 4 + i) * 4 + k];
                }
                rcB[lane] = t1 - t2 + t3 - t4;
            }
        }
        WAITLDS;

        #pragma unroll
        for (int pt = 0; pt < 2; ++pt) {
            if (lane < 16) {
                const float* cb = (const float*)zbase + pt * 1024;
                const float* rcB = cb + 320;
                const float cr = c4[pt].y, cth = c4[pt].z;
                float S, Cq;
                __sincosf(cth, &S, &Cq);
                const float E = __expf(fv[pt]);
                const float GI1 = 1.f / E;
                const float GI2 = 1.f / (cr * cr);
                const float GI3 = GI2 / (S * S);
                const int j = lane >> 2, k = lane & 3;
                const float R = -rcB[0] + GI1 * rcB[5] + GI2 * rcB[10] + GI3 * rcB[15];
                const float GIj = sel4(j, -1.f, GI1, GI2, GI3);
                const float GIk = sel4(k, -1.f, GI1, GI2, GI3);
                const float o = GIj * GIk * rcB[lane] - ((j == k) ? 0.5f * R * GIj : 0.f);
                out[(p + pt) * 16 + lane] = o;
            }
        }
        WAITLDS;   // rcB reads retired before next iteration's z-staging
    }
}

extern "C" void kernel_launch(void* const* d_in, const int* in_sizes, int n_in,
                              void* d_out, int out_size, void* d_ws, size_t ws_size,
                              hipStream_t stream) {
    const float* coords = (const float*)d_in[0];
    const float* W1 = (const float*)d_in[1];
    const float* b1 = (const float*)d_in[2];
    const float* W2 = (const float*)d_in[3];
    const float* b2 = (const float*)d_in[4];
    const float* W3 = (const float*)d_in[5];
    const float* b3 = (const float*)d_in[6];
    const float* W4 = (const float*)d_in[7];
    const float* b4 = (const float*)d_in[8];
    const int B = in_sizes[0] / 4;

    hipLaunchKernelGGL(einstein_kernel, dim3(NBLOCKS), dim3(BLOCK), 0, stream,
                       coords, W1, b1, W2, b2, W3, b3, W4, b4,
                       (float*)d_out, B);
}

// Round 9
// 143.530 us; speedup vs baseline: 2.1516x; 1.0850x over previous
//
#include <hip/hip_runtime.h>

#define NBLOCKS 4096
#define WPB 4
#define BLOCK 256

typedef __attribute__((ext_vector_type(8))) short sh8;
typedef __attribute__((ext_vector_type(4))) float f32x4;

__device__ __forceinline__ float sel4(int b, float x0, float x1, float x2, float x3) {
    float r = x3;
    r = (b == 2) ? x2 : r;
    r = (b == 1) ? x1 : r;
    r = (b == 0) ? x0 : r;
    return r;
}

__device__ __forceinline__ float fast_tanh(float x) {
    float e = __expf(2.f * x);
    return 1.f - 2.f / (e + 1.f);
}

// swizzled bf16 index into a [rows][64] LDS array (row stride = 32 dwords).
__device__ __forceinline__ int zidx(int m, int u) {
    return (((m << 5) + (((u >> 1) ^ ((m & 7) << 2)))) << 1) + (u & 1);
}

// load an 8x-bf16 MFMA fragment: row = matrix row, lanes' k-slice = kt*32 + g*8
__device__ __forceinline__ sh8 ldfrag(const unsigned short* base, int row, int g, int kt) {
    const int dw = (row << 5) + ((((kt << 4) + (g << 2))) ^ ((row & 7) << 2));
    return *(const sh8*)(base + (dw << 1));
}

// split f32 into truncated-bf16 hi and bf16(x-hi) lo
__device__ __forceinline__ void wsplit(float x, unsigned short& h, unsigned short& l) {
    const unsigned ub = __float_as_uint(x);
    const unsigned hb = ub & 0xffff0000u;
    const float lf = x - __uint_as_float(hb);
    h = (unsigned short)(hb >> 16);
    l = (unsigned short)(__float_as_uint(lf) >> 16);
}

__device__ __forceinline__ void stage15(unsigned short* zh, unsigned short* zl,
                                        const float* z, int lane) {
    #pragma unroll
    for (int m = 0; m < 15; ++m) {
        unsigned short h, l;
        wsplit(z[m], h, l);
        const int ix = zidx(m, lane);
        zh[ix] = h;
        zl[ix] = l;
    }
}

__device__ __forceinline__ void jet_nl(const float* a, float bias, float* z) {
    const float a0v = a[0] + bias;
    const float y = fast_tanh(a0v);
    const float D = 1.f - y * y;
    const float m2 = -2.f * y * D;
    z[0] = y;
    z[1] = D * a[1]; z[2] = D * a[2]; z[3] = D * a[3]; z[4] = D * a[4];
    z[5] = D * a[5] + m2 * a[1] * a[1];
    z[6] = D * a[6] + m2 * a[1] * a[2];
    z[7] = D * a[7] + m2 * a[1] * a[3];
    z[8] = D * a[8] + m2 * a[1] * a[4];
    z[9] = D * a[9] + m2 * a[2] * a[2];
    z[10] = D * a[10] + m2 * a[2] * a[3];
    z[11] = D * a[11] + m2 * a[2] * a[4];
    z[12] = D * a[12] + m2 * a[3] * a[3];
    z[13] = D * a[13] + m2 * a[3] * a[4];
    z[14] = D * a[14] + m2 * a[4] * a[4];
}

#define WAITLDS asm volatile("s_waitcnt lgkmcnt(0)" ::: "memory")

// REGISTER HISTORY: (256,5) cap 102 -> 930 MB scratch (R5). (256,4) cap 128 ->
// 56 MB scratch (R6). (256,3) cap 170 with 2-pt structure -> 45 MB scratch
// (R8: needs ~195 incl AGPR). (256,2) cap 256: allocator takes what it needs,
// no spill. Occupancy then ~2 waves/SIMD -- paid for by 2 dense chains/wave.
__global__ __launch_bounds__(BLOCK, 2) void einstein_kernel(
    const float* __restrict__ coords,
    const float* __restrict__ gW1, const float* __restrict__ gb1,
    const float* __restrict__ gW2, const float* __restrict__ gb2,
    const float* __restrict__ gW3, const float* __restrict__ gb3,
    const float* __restrict__ gW4, const float* __restrict__ gb4,
    float* __restrict__ out, int B)
{
    // weights transposed+swizzled: [layer][out 64][in 64] bf16 (hi staged first,
    // pulled to regs, then overwritten with lo residual)
    __shared__ __align__(16) unsigned short wlds[2][4096];
    // W4 reduce-GEMM B-fragments: [4 frags][64 lanes][8] bf16 (h0,h1,l0,l1)
    __shared__ __align__(16) unsigned short w4lds[2048];
    // per-wave 8 KB, 2 points x 4 KB; each 4 KB time-multiplexed:
    //   phase A: zh [0..1023] + zl [1024..2047] (bf16 jet state)
    //   phase B: cb = f32 [64][16] quad-swizzled C transpose (aliases zh/zl)
    //   phase C: reduce row + epilogue gmB/dgmB/rcB/fkB (352 f32, same region)
    __shared__ __align__(16) unsigned short zS[WPB][4096];

    const int wv = threadIdx.x >> 6;
    const int lane = threadIdx.x & 63;
    const int n15 = lane & 15;
    const int g = lane >> 4;

    unsigned short* zbase = zS[wv];

    // ---- stage Wh (truncated-bf16) into LDS, pull fragments to registers ----
    for (int e = threadIdx.x; e < 4096; e += BLOCK) {
        const int o = e & 63, i = e >> 6;
        unsigned short h2, l2, h3, l3;
        wsplit(gW2[i * 64 + o], h2, l2);
        wsplit(gW3[i * 64 + o], h3, l3);
        const int ix = zidx(o, i);
        wlds[0][ix] = h2;
        wlds[1][ix] = h3;
    }
    // W4 B-fragments (col 0 = W4, cols 1-15 zero); all waves write identical data
    #pragma unroll
    for (int kt = 0; kt < 2; ++kt) {
        sh8 bh, bl;
        #pragma unroll
        for (int e = 0; e < 8; ++e) {
            const float v = (n15 == 0) ? gW4[kt * 32 + g * 8 + e] : 0.f;
            unsigned short h, l;
            wsplit(v, h, l);
            bh[e] = (short)h;
            bl[e] = (short)l;
        }
        *(sh8*)(w4lds + kt * 512 + (lane << 3)) = bh;
        *(sh8*)(w4lds + (2 + kt) * 512 + (lane << 3)) = bl;
    }
    __syncthreads();
    sh8 Whf[2][4][2];
    #pragma unroll
    for (int L = 0; L < 2; ++L)
        #pragma unroll
        for (int nt = 0; nt < 4; ++nt)
            #pragma unroll
            for (int kt = 0; kt < 2; ++kt)
                Whf[L][nt][kt] = ldfrag(wlds[L], nt * 16 + n15, g, kt);
    __syncthreads();
    // ---- restage with Wl (low bf16 residual) ----
    for (int e = threadIdx.x; e < 4096; e += BLOCK) {
        const int o = e & 63, i = e >> 6;
        unsigned short h2, l2, h3, l3;
        wsplit(gW2[i * 64 + o], h2, l2);
        wsplit(gW3[i * 64 + o], h3, l3);
        const int ix = zidx(o, i);
        wlds[0][ix] = l2;
        wlds[1][ix] = l3;
    }
    __syncthreads();
    // A-row 15 (jet 15) never zeroed; garbage confined to C row/col 15, unread.

    // per-lane layer-1 constants (lane = hidden unit)
    const float w1c0 = gW1[0 * 64 + lane];
    const float w1c1 = gW1[1 * 64 + lane];
    const float w1c2 = gW1[2 * 64 + lane];
    const float w1c3 = gW1[3 * 64 + lane];
    const float b1c = gb1[lane], b2c = gb2[lane], b3c = gb3[lane];
    const float b4v = gb4[0];

    const int wid = blockIdx.x * WPB + wv;
    const int nw = NBLOCKS * WPB;

    for (int p = 2 * wid; p < B; p += 2 * nw) {
        float4 c4[2];
        c4[0] = reinterpret_cast<const float4*>(coords)[p];
        c4[1] = reinterpret_cast<const float4*>(coords)[p + 1];

        float z[2][15];
        // ---------- layer 1 (4 -> 64), closed-form jet, lane = unit; both points
        #pragma unroll
        for (int pt = 0; pt < 2; ++pt) {
            const float u = b1c + c4[pt].x * w1c0 + c4[pt].y * w1c1 + c4[pt].z * w1c2 + c4[pt].w * w1c3;
            const float y = fast_tanh(u);
            const float D = 1.f - y * y;
            const float m2 = -2.f * y * D;
            z[pt][0] = y;
            z[pt][1] = D * w1c0; z[pt][2] = D * w1c1; z[pt][3] = D * w1c2; z[pt][4] = D * w1c3;
            z[pt][5] = m2 * w1c0 * w1c0; z[pt][6] = m2 * w1c0 * w1c1; z[pt][7] = m2 * w1c0 * w1c2; z[pt][8] = m2 * w1c0 * w1c3;
            z[pt][9] = m2 * w1c1 * w1c1; z[pt][10] = m2 * w1c1 * w1c2; z[pt][11] = m2 * w1c1 * w1c3;
            z[pt][12] = m2 * w1c2 * w1c2; z[pt][13] = m2 * w1c2 * w1c3; z[pt][14] = m2 * w1c3 * w1c3;
            stage15(zbase + pt * 2048, zbase + pt * 2048 + 1024, z[pt], lane);
        }
        WAITLDS;

        // ---------- layers 2,3: jet-GEMM on MFMA with hi/lo split, 2 pts interleaved
        #pragma unroll
        for (int LL = 0; LL < 2; ++LL) {
            const unsigned short* wl = wlds[LL];
            sh8 Ah0[2], Ah1[2], Al0[2], Al1[2];
            #pragma unroll
            for (int pt = 0; pt < 2; ++pt) {
                unsigned short* zh = zbase + pt * 2048;
                unsigned short* zl = zh + 1024;
                Ah0[pt] = ldfrag(zh, n15, g, 0);
                Ah1[pt] = ldfrag(zh, n15, g, 1);
                Al0[pt] = ldfrag(zl, n15, g, 0);
                Al1[pt] = ldfrag(zl, n15, g, 1);
            }
            WAITLDS;   // frag reads retired before scatter clobbers the alias
            #pragma unroll
            for (int nt = 0; nt < 4; ++nt) {
                const sh8 Bl0 = ldfrag(wl, nt * 16 + n15, g, 0);
                const sh8 Bl1 = ldfrag(wl, nt * 16 + n15, g, 1);
                #pragma unroll
                for (int pt = 0; pt < 2; ++pt) {
                    f32x4 a0 = {0.f, 0.f, 0.f, 0.f};
                    a0 = __builtin_amdgcn_mfma_f32_16x16x32_bf16(Ah0[pt], Whf[LL][nt][0], a0, 0, 0, 0);
                    a0 = __builtin_amdgcn_mfma_f32_16x16x32_bf16(Ah1[pt], Whf[LL][nt][1], a0, 0, 0, 0);
                    a0 = __builtin_amdgcn_mfma_f32_16x16x32_bf16(Al0[pt], Whf[LL][nt][0], a0, 0, 0, 0);
                    a0 = __builtin_amdgcn_mfma_f32_16x16x32_bf16(Al1[pt], Whf[LL][nt][1], a0, 0, 0, 0);
                    a0 = __builtin_amdgcn_mfma_f32_16x16x32_bf16(Ah0[pt], Bl0, a0, 0, 0, 0);
                    a0 = __builtin_amdgcn_mfma_f32_16x16x32_bf16(Ah1[pt], Bl1, a0, 0, 0, 0);
                    float* cb = (float*)zbase + pt * 1024;
                    const int u = nt * 16 + n15;
                    *(f32x4*)(cb + u * 16 + ((g << 2) ^ (u & 12))) = a0;
                }
            }
            WAITLDS;   // scatters visible
            float a[2][15];
            #pragma unroll
            for (int pt = 0; pt < 2; ++pt) {
                float* cb = (float*)zbase + pt * 1024;
                #pragma unroll
                for (int c = 0; c < 4; ++c) {
                    const f32x4 r = *(const f32x4*)(cb + lane * 16 + ((c << 2) ^ (lane & 12)));
                    #pragma unroll
                    for (int t = 0; t < 4; ++t)
                        if (c * 4 + t < 15) a[pt][c * 4 + t] = r[t];
                }
            }
            WAITLDS;   // gathers retired before restage clobbers
            #pragma unroll
            for (int pt = 0; pt < 2; ++pt) {
                jet_nl(a[pt], LL ? b3c : b2c, z[pt]);
                stage15(zbase + pt * 2048, zbase + pt * 2048 + 1024, z[pt], lane);
            }
            WAITLDS;
        }

        // ---------- final layer (64 -> 1) as MFMA reduce, shared W4 B-frags
        {
            const sh8 Bh0 = *(const sh8*)(w4lds + 0 * 512 + (lane << 3));
            const sh8 Bh1 = *(const sh8*)(w4lds + 1 * 512 + (lane << 3));
            const sh8 Bw0 = *(const sh8*)(w4lds + 2 * 512 + (lane << 3));
            const sh8 Bw1 = *(const sh8*)(w4lds + 3 * 512 + (lane << 3));
            f32x4 rs[2];
            #pragma unroll
            for (int pt = 0; pt < 2; ++pt) {
                unsigned short* zh = zbase + pt * 2048;
                unsigned short* zl = zh + 1024;
                const sh8 Ah0 = ldfrag(zh, n15, g, 0);
                const sh8 Ah1 = ldfrag(zh, n15, g, 1);
                const sh8 Al0 = ldfrag(zl, n15, g, 0);
                const sh8 Al1 = ldfrag(zl, n15, g, 1);
                f32x4 r = {0.f, 0.f, 0.f, 0.f};
                r = __builtin_amdgcn_mfma_f32_16x16x32_bf16(Ah0, Bh0, r, 0, 0, 0);
                r = __builtin_amdgcn_mfma_f32_16x16x32_bf16(Ah1, Bh1, r, 0, 0, 0);
                r = __builtin_amdgcn_mfma_f32_16x16x32_bf16(Al0, Bh0, r, 0, 0, 0);
                r = __builtin_amdgcn_mfma_f32_16x16x32_bf16(Al1, Bh1, r, 0, 0, 0);
                r = __builtin_amdgcn_mfma_f32_16x16x32_bf16(Ah0, Bw0, r, 0, 0, 0);
                r = __builtin_amdgcn_mfma_f32_16x16x32_bf16(Ah1, Bw1, r, 0, 0, 0);
                rs[pt] = r;
            }
            WAITLDS;   // frag reads retired before col-0 write clobbers zh row 0
            if (n15 == 0) {
                *(f32x4*)((float*)zbase + (g << 2)) = rs[0];
                *(f32x4*)((float*)zbase + 1024 + (g << 2)) = rs[1];
            }
        }
        WAITLDS;
        float fv[2], fja[2][4], sv[2][10];
        #pragma unroll
        for (int pt = 0; pt < 2; ++pt) {
            const float* cb = (const float*)zbase + pt * 1024;
            const f32x4 r0 = *(const f32x4*)(cb);
            const f32x4 r1 = *(const f32x4*)(cb + 4);
            const f32x4 r2 = *(const f32x4*)(cb + 8);
            const f32x4 r3 = *(const f32x4*)(cb + 12);
            fv[pt] = r0[0] + b4v;
            fja[pt][0] = r0[1]; fja[pt][1] = r0[2]; fja[pt][2] = r0[3]; fja[pt][3] = r1[0];
            sv[pt][0] = r1[1]; sv[pt][1] = r1[2]; sv[pt][2] = r1[3];
            sv[pt][3] = r2[0]; sv[pt][4] = r2[1]; sv[pt][5] = r2[2]; sv[pt][6] = r2[3];
            sv[pt][7] = r3[0]; sv[pt][8] = r3[1]; sv[pt][9] = r3[2];
        }
        WAITLDS;   // reduce reads retired before epilogue overwrites cb

        // ---------- merged Hessian staging: lanes 0-15 -> pt0, 16-31 -> pt1
        const int pt16 = (lane >> 4) & 1;
        const int sub = lane & 15;
        if (lane < 32) {
            float* fkB = (float*)zbase + pt16 * 1024 + 336;
            const int jj = sub >> 2, kk = sub & 3;
            const int lo = jj < kk ? jj : kk, hi = jj < kk ? kk : jj;
            const int code = lo * 4 + hi;
            // per-pt scalar selects (explicit ternary -> cndmask, no reg-array idx)
            const float p0 = pt16 ? sv[1][0] : sv[0][0];
            const float p1 = pt16 ? sv[1][1] : sv[0][1];
            const float p2 = pt16 ? sv[1][2] : sv[0][2];
            const float p3 = pt16 ? sv[1][3] : sv[0][3];
            const float p4 = pt16 ? sv[1][4] : sv[0][4];
            const float p5 = pt16 ? sv[1][5] : sv[0][5];
            const float p6 = pt16 ? sv[1][6] : sv[0][6];
            const float p7 = pt16 ? sv[1][7] : sv[0][7];
            const float p8 = pt16 ? sv[1][8] : sv[0][8];
            const float p9 = pt16 ? sv[1][9] : sv[0][9];
            float v = p9;
            v = code == 0 ? p0 : v;  v = code == 1 ? p1 : v;  v = code == 2 ? p2 : v;
            v = code == 3 ? p3 : v;  v = code == 5 ? p4 : v;  v = code == 6 ? p5 : v;
            v = code == 7 ? p6 : v;  v = code == 10 ? p7 : v; v = code == 11 ? p8 : v;
            fkB[sub] = v;
        }
        WAITLDS;

        // ---------- Christoffel + derivatives: full width, per-pt unrolled
        const int li = (lane >> 4) & 3, lk = (lane >> 2) & 3, lj = lane & 3;
        #pragma unroll
        for (int pt = 0; pt < 2; ++pt) {
            float* cb = (float*)zbase + pt * 1024;
            float* gmB = cb;
            float* dgmB = cb + 64;
            const float* fkB = cb + 336;
            const float cr = c4[pt].y, cth = c4[pt].z;
            float S, Cq;
            __sincosf(cth, &S, &Cq);
            const float E = __expf(fv[pt]);
            const float r2v = cr * cr, S2 = S * S;
            const float GI1 = 1.f / E;
            const float GI2 = 1.f / r2v;
            const float GI3 = GI2 / S2;
            const float d3_r = 2.f * cr * S2;
            const float d3_th = 2.f * r2v * S * Cq;
            const float dd_rr = 2.f * S2;
            const float dd_rth = 4.f * cr * S * Cq;
            const float dd_thth = 2.f * r2v * (Cq * Cq - S2);

            auto fjsel = [&](int b) { return sel4(b, fja[pt][0], fja[pt][1], fja[pt][2], fja[pt][3]); };
            auto dgd = [&](int a, int b) {
                float v1 = E * fjsel(b);
                float v2 = (b == 1) ? (2.f * cr) : 0.f;
                float v3 = (b == 1) ? d3_r : ((b == 2) ? d3_th : 0.f);
                return (a == 1) ? v1 : ((a == 2) ? v2 : ((a == 3) ? v3 : 0.f));
            };
            auto d2f = [&](int a, int b, int l) {
                float v1 = E * (fjsel(b) * fjsel(l) + fkB[b * 4 + l]);
                float v2 = (b == 1 && l == 1) ? 2.f : 0.f;
                float v3 = (b == 1 && l == 1) ? dd_rr
                           : (((b == 1 && l == 2) || (b == 2 && l == 1)) ? dd_rth
                           : ((b == 2 && l == 2) ? dd_thth : 0.f));
                return (a == 1) ? v1 : ((a == 2) ? v2 : ((a == 3) ? v3 : 0.f));
            };

            const float GIi = sel4(li, -1.f, GI1, GI2, GI3);
            float P = (lk == li ? dgd(li, lj) : 0.f)
                    + (lj == li ? dgd(li, lk) : 0.f)
                    - (lj == lk ? dgd(lj, li) : 0.f);
            gmB[lane] = 0.5f * GIi * P;
            const float GIi2 = GIi * GIi;
            float Q0 = (lk == li ? d2f(li, lj, 0) : 0.f) + (lj == li ? d2f(li, lk, 0) : 0.f) - (lj == lk ? d2f(lj, li, 0) : 0.f);
            float Q1 = (lk == li ? d2f(li, lj, 1) : 0.f) + (lj == li ? d2f(li, lk, 1) : 0.f) - (lj == lk ? d2f(lj, li, 1) : 0.f);
            float Q2 = (lk == li ? d2f(li, lj, 2) : 0.f) + (lj == li ? d2f(li, lk, 2) : 0.f) - (lj == lk ? d2f(lj, li, 2) : 0.f);
            float Q3 = (lk == li ? d2f(li, lj, 3) : 0.f) + (lj == li ? d2f(li, lk, 3) : 0.f) - (lj == lk ? d2f(lj, li, 3) : 0.f);
            const float dgm0 = 0.5f * (GIi * Q0 - dgd(li, 0) * GIi2 * P);
            const float dgm1 = 0.5f * (GIi * Q1 - dgd(li, 1) * GIi2 * P);
            const float dgm2 = 0.5f * (GIi * Q2 - dgd(li, 2) * GIi2 * P);
            const float dgm3 = 0.5f * (GIi * Q3 - dgd(li, 3) * GIi2 * P);
            reinterpret_cast<float4*>(dgmB)[lane] = make_float4(dgm0, dgm1, dgm2, dgm3);
        }
        WAITLDS;

        // ---------- merged Ricci contraction: lanes 0-15 -> pt0, 16-31 -> pt1
        if (lane < 32) {
            float* cb = (float*)zbase + pt16 * 1024;
            const float* gmB = cb;
            const float* dgmB = cb + 64;
            float* rcB = cb + 320;
            const int j = sub >> 2, k = sub & 3;
            float T0 = 0, T1 = 0, T2 = 0, T3 = 0;
            #pragma unroll
            for (int i = 0; i < 4; ++i) {
                T0 += gmB[i * 16 + 0 + i];
                T1 += gmB[i * 16 + 4 + i];
                T2 += gmB[i * 16 + 8 + i];
                T3 += gmB[i * 16 + 12 + i];
            }
            float t1 = gmB[0 + j * 4 + k] * T0 + gmB[16 + j * 4 + k] * T1
                     + gmB[32 + j * 4 + k] * T2 + gmB[48 + j * 4 + k] * T3;
            float t2 = 0.f;
            #pragma unroll
            for (int m = 0; m < 4; ++m)
                #pragma unroll
                for (int i = 0; i < 4; ++i)
                    t2 += gmB[m * 16 + j * 4 + i] * gmB[i * 16 + m * 4 + k];
            float t3 = 0.f, t4 = 0.f;
            #pragma unroll
            for (int i = 0; i < 4; ++i) {
                t3 += dgmB[(i * 16 + j * 4 + k) * 4 + i];
                t4 += dgmB[(i * 16 + j * 4 + i) * 4 + k];
            }
            rcB[sub] = t1 - t2 + t3 - t4;
        }
        WAITLDS;

        // ---------- merged Einstein assembly + store: lanes 0-31
        if (lane < 32) {
            const float* cb = (const float*)zbase + pt16 * 1024;
            const float* rcB = cb + 320;
            const float cr = pt16 ? c4[1].y : c4[0].y;
            const float cth = pt16 ? c4[1].z : c4[0].z;
            const float fvp = pt16 ? fv[1] : fv[0];
            float S, Cq;
            __sincosf(cth, &S, &Cq);
            const float E = __expf(fvp);
            const float GI1 = 1.f / E;
            const float GI2 = 1.f / (cr * cr);
            const float GI3 = GI2 / (S * S);
            const int j = sub >> 2, k = sub & 3;
            const float R = -rcB[0] + GI1 * rcB[5] + GI2 * rcB[10] + GI3 * rcB[15];
            const float GIj = sel4(j, -1.f, GI1, GI2, GI3);
            const float GIk = sel4(k, -1.f, GI1, GI2, GI3);
            const float o = GIj * GIk * rcB[sub] - ((j == k) ? 0.5f * R * GIj : 0.f);
            out[(p + pt16) * 16 + sub] = o;
        }
        WAITLDS;   // rcB reads retired before next iteration's z-staging
    }
}

extern "C" void kernel_launch(void* const* d_in, const int* in_sizes, int n_in,
                              void* d_out, int out_size, void* d_ws, size_t ws_size,
                              hipStream_t stream) {
    const float* coords = (const float*)d_in[0];
    const float* W1 = (const float*)d_in[1];
    const float* b1 = (const float*)d_in[2];
    const float* W2 = (const float*)d_in[3];
    const float* b2 = (const float*)d_in[4];
    const float* W3 = (const float*)d_in[5];
    const float* b3 = (const float*)d_in[6];
    const float* W4 = (const float*)d_in[7];
    const float* b4 = (const float*)d_in[8];
    const int B = in_sizes[0] / 4;

    hipLaunchKernelGGL(einstein_kernel, dim3(NBLOCKS), dim3(BLOCK), 0, stream,
                       coords, W1, b1, W2, b2, W3, b3, W4, b4,
                       (float*)d_out, B);
}

// Round 10
// 142.432 us; speedup vs baseline: 2.1682x; 1.0077x over previous
//
#include <hip/hip_runtime.h>

#define NBLOCKS 4096
#define WPB 4
#define BLOCK 256

typedef __attribute__((ext_vector_type(8))) short sh8;
typedef __attribute__((ext_vector_type(4))) float f32x4;

__device__ __forceinline__ float sel4(int b, float x0, float x1, float x2, float x3) {
    float r = x3;
    r = (b == 2) ? x2 : r;
    r = (b == 1) ? x1 : r;
    r = (b == 0) ? x0 : r;
    return r;
}

__device__ __forceinline__ float fast_tanh(float x) {
    float e = __expf(2.f * x);
    return 1.f - 2.f / (e + 1.f);
}

// swizzled bf16 index into a [rows][64] LDS array (row stride = 32 dwords).
__device__ __forceinline__ int zidx(int m, int u) {
    return (((m << 5) + (((u >> 1) ^ ((m & 7) << 2)))) << 1) + (u & 1);
}

// load an 8x-bf16 MFMA fragment: row = matrix row, lanes' k-slice = kt*32 + g*8
__device__ __forceinline__ sh8 ldfrag(const unsigned short* base, int row, int g, int kt) {
    const int dw = (row << 5) + ((((kt << 4) + (g << 2))) ^ ((row & 7) << 2));
    return *(const sh8*)(base + (dw << 1));
}

// split f32 into truncated-bf16 hi and bf16(x-hi) lo
__device__ __forceinline__ void wsplit(float x, unsigned short& h, unsigned short& l) {
    const unsigned ub = __float_as_uint(x);
    const unsigned hb = ub & 0xffff0000u;
    const float lf = x - __uint_as_float(hb);
    h = (unsigned short)(hb >> 16);
    l = (unsigned short)(__float_as_uint(lf) >> 16);
}

__device__ __forceinline__ void stage15(unsigned short* zh, unsigned short* zl,
                                        const float* z, int lane) {
    #pragma unroll
    for (int m = 0; m < 15; ++m) {
        unsigned short h, l;
        wsplit(z[m], h, l);
        const int ix = zidx(m, lane);
        zh[ix] = h;
        zl[ix] = l;
    }
}

__device__ __forceinline__ void jet_nl(const float* a, float bias, float* z) {
    const float a0v = a[0] + bias;
    const float y = fast_tanh(a0v);
    const float D = 1.f - y * y;
    const float m2 = -2.f * y * D;
    z[0] = y;
    z[1] = D * a[1]; z[2] = D * a[2]; z[3] = D * a[3]; z[4] = D * a[4];
    z[5] = D * a[5] + m2 * a[1] * a[1];
    z[6] = D * a[6] + m2 * a[1] * a[2];
    z[7] = D * a[7] + m2 * a[1] * a[3];
    z[8] = D * a[8] + m2 * a[1] * a[4];
    z[9] = D * a[9] + m2 * a[2] * a[2];
    z[10] = D * a[10] + m2 * a[2] * a[3];
    z[11] = D * a[11] + m2 * a[2] * a[4];
    z[12] = D * a[12] + m2 * a[3] * a[3];
    z[13] = D * a[13] + m2 * a[3] * a[4];
    z[14] = D * a[14] + m2 * a[4] * a[4];
}

// Phase fence: COMPILER-ONLY reordering barrier (no instruction emitted).
// All LDS hazards in the loop are same-wave DS-to-DS (per-wave buffers); the
// DS pipe executes a wave's ops in program order, so no s_waitcnt drain is
// needed -- the compiler still inserts counted lgkmcnt for register deps.
// (R9 used s_waitcnt lgkmcnt(0) here: ~15 full drains/iter, self-serialization.)
#define WAITLDS asm volatile("" ::: "memory")

// REGISTER HISTORY: (256,5) cap 102 -> 930 MB scratch (R5). (256,4) cap 128 ->
// 56 MB scratch (R6). (256,3) cap 170 with 2-pt structure -> 45 MB scratch
// (R8: needs ~195 incl AGPR). (256,2) cap 256: no spill (R9: WRITE=4MB).
__global__ __launch_bounds__(BLOCK, 2) void einstein_kernel(
    const float* __restrict__ coords,
    const float* __restrict__ gW1, const float* __restrict__ gb1,
    const float* __restrict__ gW2, const float* __restrict__ gb2,
    const float* __restrict__ gW3, const float* __restrict__ gb3,
    const float* __restrict__ gW4, const float* __restrict__ gb4,
    float* __restrict__ out, int B)
{
    __shared__ __align__(16) unsigned short wlds[2][4096];
    __shared__ __align__(16) unsigned short w4lds[2048];
    __shared__ __align__(16) unsigned short zS[WPB][4096];

    const int wv = threadIdx.x >> 6;
    const int lane = threadIdx.x & 63;
    const int n15 = lane & 15;
    const int g = lane >> 4;

    unsigned short* zbase = zS[wv];

    // ---- stage Wh (truncated-bf16) into LDS, pull fragments to registers ----
    for (int e = threadIdx.x; e < 4096; e += BLOCK) {
        const int o = e & 63, i = e >> 6;
        unsigned short h2, l2, h3, l3;
        wsplit(gW2[i * 64 + o], h2, l2);
        wsplit(gW3[i * 64 + o], h3, l3);
        const int ix = zidx(o, i);
        wlds[0][ix] = h2;
        wlds[1][ix] = h3;
    }
    // W4 B-fragments (col 0 = W4, cols 1-15 zero); all waves write identical data
    #pragma unroll
    for (int kt = 0; kt < 2; ++kt) {
        sh8 bh, bl;
        #pragma unroll
        for (int e = 0; e < 8; ++e) {
            const float v = (n15 == 0) ? gW4[kt * 32 + g * 8 + e] : 0.f;
            unsigned short h, l;
            wsplit(v, h, l);
            bh[e] = (short)h;
            bl[e] = (short)l;
        }
        *(sh8*)(w4lds + kt * 512 + (lane << 3)) = bh;
        *(sh8*)(w4lds + (2 + kt) * 512 + (lane << 3)) = bl;
    }
    __syncthreads();
    sh8 Whf[2][4][2];
    #pragma unroll
    for (int L = 0; L < 2; ++L)
        #pragma unroll
        for (int nt = 0; nt < 4; ++nt)
            #pragma unroll
            for (int kt = 0; kt < 2; ++kt)
                Whf[L][nt][kt] = ldfrag(wlds[L], nt * 16 + n15, g, kt);
    __syncthreads();
    // ---- restage with Wl (low bf16 residual) ----
    for (int e = threadIdx.x; e < 4096; e += BLOCK) {
        const int o = e & 63, i = e >> 6;
        unsigned short h2, l2, h3, l3;
        wsplit(gW2[i * 64 + o], h2, l2);
        wsplit(gW3[i * 64 + o], h3, l3);
        const int ix = zidx(o, i);
        wlds[0][ix] = l2;
        wlds[1][ix] = l3;
    }
    __syncthreads();
    // A-row 15 (jet 15) never zeroed; garbage confined to C row/col 15, unread.

    // per-lane layer-1 constants (lane = hidden unit)
    const float w1c0 = gW1[0 * 64 + lane];
    const float w1c1 = gW1[1 * 64 + lane];
    const float w1c2 = gW1[2 * 64 + lane];
    const float w1c3 = gW1[3 * 64 + lane];
    const float b1c = gb1[lane], b2c = gb2[lane], b3c = gb3[lane];
    const float b4v = gb4[0];

    const int wid = blockIdx.x * WPB + wv;
    const int nw = NBLOCKS * WPB;

    for (int p = 2 * wid; p < B; p += 2 * nw) {
        float4 c4[2];
        c4[0] = reinterpret_cast<const float4*>(coords)[p];
        c4[1] = reinterpret_cast<const float4*>(coords)[p + 1];

        float z[2][15];
        // ---------- layer 1 (4 -> 64), closed-form jet, lane = unit; both points
        #pragma unroll
        for (int pt = 0; pt < 2; ++pt) {
            const float u = b1c + c4[pt].x * w1c0 + c4[pt].y * w1c1 + c4[pt].z * w1c2 + c4[pt].w * w1c3;
            const float y = fast_tanh(u);
            const float D = 1.f - y * y;
            const float m2 = -2.f * y * D;
            z[pt][0] = y;
            z[pt][1] = D * w1c0; z[pt][2] = D * w1c1; z[pt][3] = D * w1c2; z[pt][4] = D * w1c3;
            z[pt][5] = m2 * w1c0 * w1c0; z[pt][6] = m2 * w1c0 * w1c1; z[pt][7] = m2 * w1c0 * w1c2; z[pt][8] = m2 * w1c0 * w1c3;
            z[pt][9] = m2 * w1c1 * w1c1; z[pt][10] = m2 * w1c1 * w1c2; z[pt][11] = m2 * w1c1 * w1c3;
            z[pt][12] = m2 * w1c2 * w1c2; z[pt][13] = m2 * w1c2 * w1c3; z[pt][14] = m2 * w1c3 * w1c3;
            stage15(zbase + pt * 2048, zbase + pt * 2048 + 1024, z[pt], lane);
        }
        WAITLDS;

        // ---------- layers 2,3: jet-GEMM on MFMA with hi/lo split, 2 pts interleaved
        #pragma unroll
        for (int LL = 0; LL < 2; ++LL) {
            const unsigned short* wl = wlds[LL];
            sh8 Ah0[2], Ah1[2], Al0[2], Al1[2];
            #pragma unroll
            for (int pt = 0; pt < 2; ++pt) {
                unsigned short* zh = zbase + pt * 2048;
                unsigned short* zl = zh + 1024;
                Ah0[pt] = ldfrag(zh, n15, g, 0);
                Ah1[pt] = ldfrag(zh, n15, g, 1);
                Al0[pt] = ldfrag(zl, n15, g, 0);
                Al1[pt] = ldfrag(zl, n15, g, 1);
            }
            WAITLDS;   // fence: frag reads ordered before scatter (same-wave DS in-order)
            #pragma unroll
            for (int nt = 0; nt < 4; ++nt) {
                const sh8 Bl0 = ldfrag(wl, nt * 16 + n15, g, 0);
                const sh8 Bl1 = ldfrag(wl, nt * 16 + n15, g, 1);
                #pragma unroll
                for (int pt = 0; pt < 2; ++pt) {
                    f32x4 a0 = {0.f, 0.f, 0.f, 0.f};
                    a0 = __builtin_amdgcn_mfma_f32_16x16x32_bf16(Ah0[pt], Whf[LL][nt][0], a0, 0, 0, 0);
                    a0 = __builtin_amdgcn_mfma_f32_16x16x32_bf16(Ah1[pt], Whf[LL][nt][1], a0, 0, 0, 0);
                    a0 = __builtin_amdgcn_mfma_f32_16x16x32_bf16(Al0[pt], Whf[LL][nt][0], a0, 0, 0, 0);
                    a0 = __builtin_amdgcn_mfma_f32_16x16x32_bf16(Al1[pt], Whf[LL][nt][1], a0, 0, 0, 0);
                    a0 = __builtin_amdgcn_mfma_f32_16x16x32_bf16(Ah0[pt], Bl0, a0, 0, 0, 0);
                    a0 = __builtin_amdgcn_mfma_f32_16x16x32_bf16(Ah1[pt], Bl1, a0, 0, 0, 0);
                    float* cb = (float*)zbase + pt * 1024;
                    const int u = nt * 16 + n15;
                    *(f32x4*)(cb + u * 16 + ((g << 2) ^ (u & 12))) = a0;
                }
            }
            WAITLDS;   // fence: scatters ordered before gathers
            float a[2][15];
            #pragma unroll
            for (int pt = 0; pt < 2; ++pt) {
                float* cb = (float*)zbase + pt * 1024;
                #pragma unroll
                for (int c = 0; c < 4; ++c) {
                    const f32x4 r = *(const f32x4*)(cb + lane * 16 + ((c << 2) ^ (lane & 12)));
                    #pragma unroll
                    for (int t = 0; t < 4; ++t)
                        if (c * 4 + t < 15) a[pt][c * 4 + t] = r[t];
                }
            }
            WAITLDS;   // fence: gathers ordered before restage
            #pragma unroll
            for (int pt = 0; pt < 2; ++pt) {
                jet_nl(a[pt], LL ? b3c : b2c, z[pt]);
                stage15(zbase + pt * 2048, zbase + pt * 2048 + 1024, z[pt], lane);
            }
            WAITLDS;
        }

        // ---------- final layer (64 -> 1) as MFMA reduce, shared W4 B-frags
        {
            const sh8 Bh0 = *(const sh8*)(w4lds + 0 * 512 + (lane << 3));
            const sh8 Bh1 = *(const sh8*)(w4lds + 1 * 512 + (lane << 3));
            const sh8 Bw0 = *(const sh8*)(w4lds + 2 * 512 + (lane << 3));
            const sh8 Bw1 = *(const sh8*)(w4lds + 3 * 512 + (lane << 3));
            f32x4 rs[2];
            #pragma unroll
            for (int pt = 0; pt < 2; ++pt) {
                unsigned short* zh = zbase + pt * 2048;
                unsigned short* zl = zh + 1024;
                const sh8 Ah0 = ldfrag(zh, n15, g, 0);
                const sh8 Ah1 = ldfrag(zh, n15, g, 1);
                const sh8 Al0 = ldfrag(zl, n15, g, 0);
                const sh8 Al1 = ldfrag(zl, n15, g, 1);
                f32x4 r = {0.f, 0.f, 0.f, 0.f};
                r = __builtin_amdgcn_mfma_f32_16x16x32_bf16(Ah0, Bh0, r, 0, 0, 0);
                r = __builtin_amdgcn_mfma_f32_16x16x32_bf16(Ah1, Bh1, r, 0, 0, 0);
                r = __builtin_amdgcn_mfma_f32_16x16x32_bf16(Al0, Bh0, r, 0, 0, 0);
                r = __builtin_amdgcn_mfma_f32_16x16x32_bf16(Al1, Bh1, r, 0, 0, 0);
                r = __builtin_amdgcn_mfma_f32_16x16x32_bf16(Ah0, Bw0, r, 0, 0, 0);
                r = __builtin_amdgcn_mfma_f32_16x16x32_bf16(Ah1, Bw1, r, 0, 0, 0);
                rs[pt] = r;
            }
            WAITLDS;   // fence: final frag reads ordered before col-0 writes
            if (n15 == 0) {
                *(f32x4*)((float*)zbase + (g << 2)) = rs[0];
                *(f32x4*)((float*)zbase + 1024 + (g << 2)) = rs[1];
            }
        }
        WAITLDS;
        float fv[2], fja[2][4], sv[2][10];
        #pragma unroll
        for (int pt = 0; pt < 2; ++pt) {
            const float* cb = (const float*)zbase + pt * 1024;
            const f32x4 r0 = *(const f32x4*)(cb);
            const f32x4 r1 = *(const f32x4*)(cb + 4);
            const f32x4 r2 = *(const f32x4*)(cb + 8);
            const f32x4 r3 = *(const f32x4*)(cb + 12);
            fv[pt] = r0[0] + b4v;
            fja[pt][0] = r0[1]; fja[pt][1] = r0[2]; fja[pt][2] = r0[3]; fja[pt][3] = r1[0];
            sv[pt][0] = r1[1]; sv[pt][1] = r1[2]; sv[pt][2] = r1[3];
            sv[pt][3] = r2[0]; sv[pt][4] = r2[1]; sv[pt][5] = r2[2]; sv[pt][6] = r2[3];
            sv[pt][7] = r3[0]; sv[pt][8] = r3[1]; sv[pt][9] = r3[2];
        }
        WAITLDS;

        // ---------- merged Hessian staging: lanes 0-15 -> pt0, 16-31 -> pt1
        const int pt16 = (lane >> 4) & 1;
        const int sub = lane & 15;
        if (lane < 32) {
            float* fkB = (float*)zbase + pt16 * 1024 + 336;
            const int jj = sub >> 2, kk = sub & 3;
            const int lo = jj < kk ? jj : kk, hi = jj < kk ? kk : jj;
            const int code = lo * 4 + hi;
            const float p0 = pt16 ? sv[1][0] : sv[0][0];
            const float p1 = pt16 ? sv[1][1] : sv[0][1];
            const float p2 = pt16 ? sv[1][2] : sv[0][2];
            const float p3 = pt16 ? sv[1][3] : sv[0][3];
            const float p4 = pt16 ? sv[1][4] : sv[0][4];
            const float p5 = pt16 ? sv[1][5] : sv[0][5];
            const float p6 = pt16 ? sv[1][6] : sv[0][6];
            const float p7 = pt16 ? sv[1][7] : sv[0][7];
            const float p8 = pt16 ? sv[1][8] : sv[0][8];
            const float p9 = pt16 ? sv[1][9] : sv[0][9];
            float v = p9;
            v = code == 0 ? p0 : v;  v = code == 1 ? p1 : v;  v = code == 2 ? p2 : v;
            v = code == 3 ? p3 : v;  v = code == 5 ? p4 : v;  v = code == 6 ? p5 : v;
            v = code == 7 ? p6 : v;  v = code == 10 ? p7 : v; v = code == 11 ? p8 : v;
            fkB[sub] = v;
        }
        WAITLDS;

        // ---------- Christoffel + derivatives: full width, per-pt unrolled
        const int li = (lane >> 4) & 3, lk = (lane >> 2) & 3, lj = lane & 3;
        #pragma unroll
        for (int pt = 0; pt < 2; ++pt) {
            float* cb = (float*)zbase + pt * 1024;
            float* gmB = cb;
            float* dgmB = cb + 64;
            const float* fkB = cb + 336;
            const float cr = c4[pt].y, cth = c4[pt].z;
            float S, Cq;
            __sincosf(cth, &S, &Cq);
            const float E = __expf(fv[pt]);
            const float r2v = cr * cr, S2 = S * S;
            const float GI1 = 1.f / E;
            const float GI2 = 1.f / r2v;
            const float GI3 = GI2 / S2;
            const float d3_r = 2.f * cr * S2;
            const float d3_th = 2.f * r2v * S * Cq;
            const float dd_rr = 2.f * S2;
            const float dd_rth = 4.f * cr * S * Cq;
            const float dd_thth = 2.f * r2v * (Cq * Cq - S2);

            auto fjsel = [&](int b) { return sel4(b, fja[pt][0], fja[pt][1], fja[pt][2], fja[pt][3]); };
            auto dgd = [&](int a, int b) {
                float v1 = E * fjsel(b);
                float v2 = (b == 1) ? (2.f * cr) : 0.f;
                float v3 = (b == 1) ? d3_r : ((b == 2) ? d3_th : 0.f);
                return (a == 1) ? v1 : ((a == 2) ? v2 : ((a == 3) ? v3 : 0.f));
            };
            auto d2f = [&](int a, int b, int l) {
                float v1 = E * (fjsel(b) * fjsel(l) + fkB[b * 4 + l]);
                float v2 = (b == 1 && l == 1) ? 2.f : 0.f;
                float v3 = (b == 1 && l == 1) ? dd_rr
                           : (((b == 1 && l == 2) || (b == 2 && l == 1)) ? dd_rth
                           : ((b == 2 && l == 2) ? dd_thth : 0.f));
                return (a == 1) ? v1 : ((a == 2) ? v2 : ((a == 3) ? v3 : 0.f));
            };

            const float GIi = sel4(li, -1.f, GI1, GI2, GI3);
            float P = (lk == li ? dgd(li, lj) : 0.f)
                    + (lj == li ? dgd(li, lk) : 0.f)
                    - (lj == lk ? dgd(lj, li) : 0.f);
            gmB[lane] = 0.5f * GIi * P;
            const float GIi2 = GIi * GIi;
            float Q0 = (lk == li ? d2f(li, lj, 0) : 0.f) + (lj == li ? d2f(li, lk, 0) : 0.f) - (lj == lk ? d2f(lj, li, 0) : 0.f);
            float Q1 = (lk == li ? d2f(li, lj, 1) : 0.f) + (lj == li ? d2f(li, lk, 1) : 0.f) - (lj == lk ? d2f(lj, li, 1) : 0.f);
            float Q2 = (lk == li ? d2f(li, lj, 2) : 0.f) + (lj == li ? d2f(li, lk, 2) : 0.f) - (lj == lk ? d2f(lj, li, 2) : 0.f);
            float Q3 = (lk == li ? d2f(li, lj, 3) : 0.f) + (lj == li ? d2f(li, lk, 3) : 0.f) - (lj == lk ? d2f(lj, li, 3) : 0.f);
            const float dgm0 = 0.5f * (GIi * Q0 - dgd(li, 0) * GIi2 * P);
            const float dgm1 = 0.5f * (GIi * Q1 - dgd(li, 1) * GIi2 * P);
            const float dgm2 = 0.5f * (GIi * Q2 - dgd(li, 2) * GIi2 * P);
            const float dgm3 = 0.5f * (GIi * Q3 - dgd(li, 3) * GIi2 * P);
            reinterpret_cast<float4*>(dgmB)[lane] = make_float4(dgm0, dgm1, dgm2, dgm3);
        }
        WAITLDS;

        // ---------- merged Ricci contraction: lanes 0-15 -> pt0, 16-31 -> pt1
        if (lane < 32) {
            float* cb = (float*)zbase + pt16 * 1024;
            const float* gmB = cb;
            const float* dgmB = cb + 64;
            float* rcB = cb + 320;
            const int j = sub >> 2, k = sub & 3;
            float T0 = 0, T1 = 0, T2 = 0, T3 = 0;
            #pragma unroll
            for (int i = 0; i < 4; ++i) {
                T0 += gmB[i * 16 + 0 + i];
                T1 += gmB[i * 16 + 4 + i];
                T2 += gmB[i * 16 + 8 + i];
                T3 += gmB[i * 16 + 12 + i];
            }
            float t1 = gmB[0 + j * 4 + k] * T0 + gmB[16 + j * 4 + k] * T1
                     + gmB[32 + j * 4 + k] * T2 + gmB[48 + j * 4 + k] * T3;
            float t2 = 0.f;
            #pragma unroll
            for (int m = 0; m < 4; ++m)
                #pragma unroll
                for (int i = 0; i < 4; ++i)
                    t2 += gmB[m * 16 + j * 4 + i] * gmB[i * 16 + m * 4 + k];
            float t3 = 0.f, t4 = 0.f;
            #pragma unroll
            for (int i = 0; i < 4; ++i) {
                t3 += dgmB[(i * 16 + j * 4 + k) * 4 + i];
                t4 += dgmB[(i * 16 + j * 4 + i) * 4 + k];
            }
            rcB[sub] = t1 - t2 + t3 - t4;
        }
        WAITLDS;

        // ---------- merged Einstein assembly + store: lanes 0-31
        if (lane < 32) {
            const float* cb = (const float*)zbase + pt16 * 1024;
            const float* rcB = cb + 320;
            const float cr = pt16 ? c4[1].y : c4[0].y;
            const float cth = pt16 ? c4[1].z : c4[0].z;
            const float fvp = pt16 ? fv[1] : fv[0];
            float S, Cq;
            __sincosf(cth, &S, &Cq);
            const float E = __expf(fvp);
            const float GI1 = 1.f / E;
            const float GI2 = 1.f / (cr * cr);
            const float GI3 = GI2 / (S * S);
            const int j = sub >> 2, k = sub & 3;
            const float R = -rcB[0] + GI1 * rcB[5] + GI2 * rcB[10] + GI3 * rcB[15];
            const float GIj = sel4(j, -1.f, GI1, GI2, GI3);
            const float GIk = sel4(k, -1.f, GI1, GI2, GI3);
            const float o = GIj * GIk * rcB[sub] - ((j == k) ? 0.5f * R * GIj : 0.f);
            out[(p + pt16) * 16 + sub] = o;
        }
        WAITLDS;
    }
}

extern "C" void kernel_launch(void* const* d_in, const int* in_sizes, int n_in,
                              void* d_out, int out_size, void* d_ws, size_t ws_size,
                              hipStream_t stream) {
    const float* coords = (const float*)d_in[0];
    const float* W1 = (const float*)d_in[1];
    const float* b1 = (const float*)d_in[2];
    const float* W2 = (const float*)d_in[3];
    const float* b2 = (const float*)d_in[4];
    const float* W3 = (const float*)d_in[5];
    const float* b3 = (const float*)d_in[6];
    const float* W4 = (const float*)d_in[7];
    const float* b4 = (const float*)d_in[8];
    const int B = in_sizes[0] / 4;

    hipLaunchKernelGGL(einstein_kernel, dim3(NBLOCKS), dim3(BLOCK), 0, stream,
                       coords, W1, b1, W2, b2, W3, b3, W4, b4,
                       (float*)d_out, B);
}

// Round 11
// 94.993 us; speedup vs baseline: 3.2510x; 1.4994x over previous
//
#include <hip/hip_runtime.h>

#define NBLOCKS 4096
#define WPB 4
#define BLOCK 256

typedef __attribute__((ext_vector_type(8))) short sh8;
typedef __attribute__((ext_vector_type(4))) float f32x4;

__device__ __forceinline__ float sel4(int b, float x0, float x1, float x2, float x3) {
    float r = x3;
    r = (b == 2) ? x2 : r;
    r = (b == 1) ? x1 : r;
    r = (b == 0) ? x0 : r;
    return r;
}

__device__ __forceinline__ float fast_tanh(float x) {
    float e = __expf(2.f * x);
    return 1.f - 2.f / (e + 1.f);
}

// swizzled bf16 index into a [rows][64] LDS array (row stride = 32 dwords).
__device__ __forceinline__ int zidx(int m, int u) {
    return (((m << 5) + (((u >> 1) ^ ((m & 7) << 2)))) << 1) + (u & 1);
}

// load an 8x-bf16 MFMA fragment: row = matrix row, lanes' k-slice = kt*32 + g*8
__device__ __forceinline__ sh8 ldfrag(const unsigned short* base, int row, int g, int kt) {
    const int dw = (row << 5) + ((((kt << 4) + (g << 2))) ^ ((row & 7) << 2));
    return *(const sh8*)(base + (dw << 1));
}

// round-to-nearest-even bf16
__device__ __forceinline__ unsigned short rtn_bf16(float x) {
    unsigned u = __float_as_uint(x);
    u += 0x7FFFu + ((u >> 16) & 1u);
    return (unsigned short)(u >> 16);
}

// split f32 into truncated-bf16 hi and bf16(x-hi) lo  (used for W4 only)
__device__ __forceinline__ void wsplit(float x, unsigned short& h, unsigned short& l) {
    const unsigned ub = __float_as_uint(x);
    const unsigned hb = ub & 0xffff0000u;
    const float lf = x - __uint_as_float(hb);
    h = (unsigned short)(hb >> 16);
    l = (unsigned short)(__float_as_uint(lf) >> 16);
}

__device__ __forceinline__ void stage15s(unsigned short* zh, const float* z, int lane) {
    #pragma unroll
    for (int m = 0; m < 15; ++m)
        zh[zidx(m, lane)] = rtn_bf16(z[m]);
}

__device__ __forceinline__ void jet_nl(const float* a, float bias, float* z) {
    const float a0v = a[0] + bias;
    const float y = fast_tanh(a0v);
    const float D = 1.f - y * y;
    const float m2 = -2.f * y * D;
    z[0] = y;
    z[1] = D * a[1]; z[2] = D * a[2]; z[3] = D * a[3]; z[4] = D * a[4];
    z[5] = D * a[5] + m2 * a[1] * a[1];
    z[6] = D * a[6] + m2 * a[1] * a[2];
    z[7] = D * a[7] + m2 * a[1] * a[3];
    z[8] = D * a[8] + m2 * a[1] * a[4];
    z[9] = D * a[9] + m2 * a[2] * a[2];
    z[10] = D * a[10] + m2 * a[2] * a[3];
    z[11] = D * a[11] + m2 * a[2] * a[4];
    z[12] = D * a[12] + m2 * a[3] * a[3];
    z[13] = D * a[13] + m2 * a[3] * a[4];
    z[14] = D * a[14] + m2 * a[4] * a[4];
}

// compiler-only reordering fence (R10: full lgkmcnt(0) drains were neutral;
// same-wave DS is in-order, so ordering at IR level suffices)
#define WAITLDS asm volatile("" ::: "memory")

// PRECISION LEDGER: state = single RTN bf16; W2/W3 = single RTN bf16 (no Whf
// register block, no Wl residual); W1 = f32 per-lane; W4 = hi/lo bf16 pair.
// absmax was 512 for both fp32 and hi/lo paths; threshold 1.024e4.
// REGISTER HISTORY: (256,5)->930MB scratch; (256,4) old struct -> 56MB;
// (256,3) 2pt hi/lo -> 45MB. This struct: ~110-125 arch regs, no AGPR block
// -> (256,4) cap 128 should fit. Spill signature = WRITE_SIZE >> 4MB.
__global__ __launch_bounds__(BLOCK, 4) void einstein_kernel(
    const float* __restrict__ coords,
    const float* __restrict__ gW1, const float* __restrict__ gb1,
    const float* __restrict__ gW2, const float* __restrict__ gb2,
    const float* __restrict__ gW3, const float* __restrict__ gb3,
    const float* __restrict__ gW4, const float* __restrict__ gb4,
    float* __restrict__ out, int B)
{
    // W2/W3 single-bf16, transposed+swizzled: [layer][out 64][in 64]
    __shared__ __align__(16) unsigned short wlds[2][4096];
    // W4 reduce B-fragments: [h0,h1,l0,l1][64 lanes][8] bf16
    __shared__ __align__(16) unsigned short w4lds[2048];
    // per-wave 4 KB, time-multiplexed:
    //   phase A: zh pt0 [0..1023] + zh pt1 [1024..2047] (bf16 jet state)
    //   phase B: cb f32[1024] = [64 u][16 m] quad-swizzled C transpose (full 4KB,
    //            serialized per point; clobbers both pts' state -> A-frags must
    //            be in regs first)
    //   phase C: reduce rows at f32 0 / 512; epilogue pt0 at 0..351, pt1 at 512..863
    __shared__ __align__(16) unsigned short zS[WPB][2048];

    const int wv = threadIdx.x >> 6;
    const int lane = threadIdx.x & 63;
    const int n15 = lane & 15;
    const int g = lane >> 4;

    unsigned short* zbase = zS[wv];
    float* cb = (float*)zbase;

    // ---- stage W2/W3 as single RTN bf16 (swizzled, transposed) ----
    for (int e = threadIdx.x; e < 4096; e += BLOCK) {
        const int o = e & 63, i = e >> 6;
        const int ix = zidx(o, i);
        wlds[0][ix] = rtn_bf16(gW2[i * 64 + o]);
        wlds[1][ix] = rtn_bf16(gW3[i * 64 + o]);
    }
    // W4 B-fragments (col 0 = W4, cols 1-15 zero), hi/lo
    #pragma unroll
    for (int kt = 0; kt < 2; ++kt) {
        sh8 bh, bl;
        #pragma unroll
        for (int e = 0; e < 8; ++e) {
            const float v = (n15 == 0) ? gW4[kt * 32 + g * 8 + e] : 0.f;
            unsigned short h, l;
            wsplit(v, h, l);
            bh[e] = (short)h;
            bl[e] = (short)l;
        }
        *(sh8*)(w4lds + kt * 512 + (lane << 3)) = bh;
        *(sh8*)(w4lds + (2 + kt) * 512 + (lane << 3)) = bl;
    }
    __syncthreads();
    // A-row 15 garbage (cb alias residue) is confined to C row 15: never read.

    // per-lane layer-1 constants (lane = hidden unit)
    const float w1c0 = gW1[0 * 64 + lane];
    const float w1c1 = gW1[1 * 64 + lane];
    const float w1c2 = gW1[2 * 64 + lane];
    const float w1c3 = gW1[3 * 64 + lane];
    const float b1c = gb1[lane], b2c = gb2[lane], b3c = gb3[lane];
    const float b4v = gb4[0];

    const int wid = blockIdx.x * WPB + wv;
    const int nw = NBLOCKS * WPB;

    for (int p = 2 * wid; p < B; p += 2 * nw) {
        float4 c4[2];
        c4[0] = reinterpret_cast<const float4*>(coords)[p];
        c4[1] = reinterpret_cast<const float4*>(coords)[p + 1];

        // ---------- layer 1 (4 -> 64), closed-form jet, lane = unit; both points
        #pragma unroll
        for (int pt = 0; pt < 2; ++pt) {
            float z[15];
            const float u = b1c + c4[pt].x * w1c0 + c4[pt].y * w1c1 + c4[pt].z * w1c2 + c4[pt].w * w1c3;
            const float y = fast_tanh(u);
            const float D = 1.f - y * y;
            const float m2 = -2.f * y * D;
            z[0] = y;
            z[1] = D * w1c0; z[2] = D * w1c1; z[3] = D * w1c2; z[4] = D * w1c3;
            z[5] = m2 * w1c0 * w1c0; z[6] = m2 * w1c0 * w1c1; z[7] = m2 * w1c0 * w1c2; z[8] = m2 * w1c0 * w1c3;
            z[9] = m2 * w1c1 * w1c1; z[10] = m2 * w1c1 * w1c2; z[11] = m2 * w1c1 * w1c3;
            z[12] = m2 * w1c2 * w1c2; z[13] = m2 * w1c2 * w1c3; z[14] = m2 * w1c3 * w1c3;
            stage15s(zbase + pt * 1024, z, lane);
        }
        WAITLDS;

        // ---------- layers 2,3: jet-GEMM on MFMA, single-bf16 A and B
        #pragma unroll
        for (int LL = 0; LL < 2; ++LL) {
            const unsigned short* wl = wlds[LL];
            sh8 A0[2], A1[2];
            #pragma unroll
            for (int pt = 0; pt < 2; ++pt) {
                A0[pt] = ldfrag(zbase + pt * 1024, n15, g, 0);
                A1[pt] = ldfrag(zbase + pt * 1024, n15, g, 1);
            }
            WAITLDS;   // frag reads ordered before scatter clobbers the alias
            f32x4 acc[2][4];
            #pragma unroll
            for (int nt = 0; nt < 4; ++nt) {
                const sh8 B0 = ldfrag(wl, nt * 16 + n15, g, 0);
                const sh8 B1 = ldfrag(wl, nt * 16 + n15, g, 1);
                #pragma unroll
                for (int pt = 0; pt < 2; ++pt) {
                    f32x4 a0 = {0.f, 0.f, 0.f, 0.f};
                    a0 = __builtin_amdgcn_mfma_f32_16x16x32_bf16(A0[pt], B0, a0, 0, 0, 0);
                    a0 = __builtin_amdgcn_mfma_f32_16x16x32_bf16(A1[pt], B1, a0, 0, 0, 0);
                    acc[pt][nt] = a0;
                }
            }
            // serialized per-pt transpose through the shared 4 KB cb
            float z0[15], z1[15];
            {
                #pragma unroll
                for (int nt = 0; nt < 4; ++nt) {
                    const int u = nt * 16 + n15;
                    *(f32x4*)(cb + u * 16 + ((g << 2) ^ (u & 12))) = acc[0][nt];
                }
                WAITLDS;
                float a[15];
                #pragma unroll
                for (int c = 0; c < 4; ++c) {
                    const f32x4 r = *(const f32x4*)(cb + lane * 16 + ((c << 2) ^ (lane & 12)));
                    #pragma unroll
                    for (int t = 0; t < 4; ++t)
                        if (c * 4 + t < 15) a[c * 4 + t] = r[t];
                }
                WAITLDS;   // pt0 gather ordered before pt1 scatter
                jet_nl(a, LL ? b3c : b2c, z0);
            }
            {
                #pragma unroll
                for (int nt = 0; nt < 4; ++nt) {
                    const int u = nt * 16 + n15;
                    *(f32x4*)(cb + u * 16 + ((g << 2) ^ (u & 12))) = acc[1][nt];
                }
                WAITLDS;
                float a[15];
                #pragma unroll
                for (int c = 0; c < 4; ++c) {
                    const f32x4 r = *(const f32x4*)(cb + lane * 16 + ((c << 2) ^ (lane & 12)));
                    #pragma unroll
                    for (int t = 0; t < 4; ++t)
                        if (c * 4 + t < 15) a[c * 4 + t] = r[t];
                }
                WAITLDS;   // pt1 gather ordered before restage clobbers
                jet_nl(a, LL ? b3c : b2c, z1);
            }
            stage15s(zbase, z0, lane);
            stage15s(zbase + 1024, z1, lane);
            WAITLDS;
        }

        // ---------- final layer (64 -> 1) as MFMA reduce, W4 hi/lo
        {
            const sh8 Bh0 = *(const sh8*)(w4lds + 0 * 512 + (lane << 3));
            const sh8 Bh1 = *(const sh8*)(w4lds + 1 * 512 + (lane << 3));
            const sh8 Bw0 = *(const sh8*)(w4lds + 2 * 512 + (lane << 3));
            const sh8 Bw1 = *(const sh8*)(w4lds + 3 * 512 + (lane << 3));
            f32x4 rs[2];
            #pragma unroll
            for (int pt = 0; pt < 2; ++pt) {
                const sh8 A0 = ldfrag(zbase + pt * 1024, n15, g, 0);
                const sh8 A1 = ldfrag(zbase + pt * 1024, n15, g, 1);
                f32x4 r = {0.f, 0.f, 0.f, 0.f};
                r = __builtin_amdgcn_mfma_f32_16x16x32_bf16(A0, Bh0, r, 0, 0, 0);
                r = __builtin_amdgcn_mfma_f32_16x16x32_bf16(A1, Bh1, r, 0, 0, 0);
                r = __builtin_amdgcn_mfma_f32_16x16x32_bf16(A0, Bw0, r, 0, 0, 0);
                r = __builtin_amdgcn_mfma_f32_16x16x32_bf16(A1, Bw1, r, 0, 0, 0);
                rs[pt] = r;
            }
            WAITLDS;   // frag reads ordered before col-0 writes
            if (n15 == 0) {
                *(f32x4*)(cb + (g << 2)) = rs[0];
                *(f32x4*)(cb + 512 + (g << 2)) = rs[1];
            }
        }
        WAITLDS;
        float fv[2], fja[2][4], sv[2][10];
        #pragma unroll
        for (int pt = 0; pt < 2; ++pt) {
            const float* cp = cb + pt * 512;
            const f32x4 r0 = *(const f32x4*)(cp);
            const f32x4 r1 = *(const f32x4*)(cp + 4);
            const f32x4 r2 = *(const f32x4*)(cp + 8);
            const f32x4 r3 = *(const f32x4*)(cp + 12);
            fv[pt] = r0[0] + b4v;
            fja[pt][0] = r0[1]; fja[pt][1] = r0[2]; fja[pt][2] = r0[3]; fja[pt][3] = r1[0];
            sv[pt][0] = r1[1]; sv[pt][1] = r1[2]; sv[pt][2] = r1[3];
            sv[pt][3] = r2[0]; sv[pt][4] = r2[1]; sv[pt][5] = r2[2]; sv[pt][6] = r2[3];
            sv[pt][7] = r3[0]; sv[pt][8] = r3[1]; sv[pt][9] = r3[2];
        }
        WAITLDS;

        // ---------- merged Hessian staging: lanes 0-15 -> pt0, 16-31 -> pt1
        const int pt16 = (lane >> 4) & 1;
        const int sub = lane & 15;
        if (lane < 32) {
            float* fkB = cb + pt16 * 512 + 336;
            const int jj = sub >> 2, kk = sub & 3;
            const int lo = jj < kk ? jj : kk, hi = jj < kk ? kk : jj;
            const int code = lo * 4 + hi;
            const float p0 = pt16 ? sv[1][0] : sv[0][0];
            const float p1 = pt16 ? sv[1][1] : sv[0][1];
            const float p2 = pt16 ? sv[1][2] : sv[0][2];
            const float p3 = pt16 ? sv[1][3] : sv[0][3];
            const float p4 = pt16 ? sv[1][4] : sv[0][4];
            const float p5 = pt16 ? sv[1][5] : sv[0][5];
            const float p6 = pt16 ? sv[1][6] : sv[0][6];
            const float p7 = pt16 ? sv[1][7] : sv[0][7];
            const float p8 = pt16 ? sv[1][8] : sv[0][8];
            const float p9 = pt16 ? sv[1][9] : sv[0][9];
            float v = p9;
            v = code == 0 ? p0 : v;  v = code == 1 ? p1 : v;  v = code == 2 ? p2 : v;
            v = code == 3 ? p3 : v;  v = code == 5 ? p4 : v;  v = code == 6 ? p5 : v;
            v = code == 7 ? p6 : v;  v = code == 10 ? p7 : v; v = code == 11 ? p8 : v;
            fkB[sub] = v;
        }
        WAITLDS;

        // ---------- Christoffel + derivatives: full width, per-pt unrolled
        const int li = (lane >> 4) & 3, lk = (lane >> 2) & 3, lj = lane & 3;
        #pragma unroll
        for (int pt = 0; pt < 2; ++pt) {
            float* cp = cb + pt * 512;
            float* gmB = cp;
            float* dgmB = cp + 64;
            const float* fkB = cp + 336;
            const float cr = c4[pt].y, cth = c4[pt].z;
            float S, Cq;
            __sincosf(cth, &S, &Cq);
            const float E = __expf(fv[pt]);
            const float r2v = cr * cr, S2 = S * S;
            const float GI1 = 1.f / E;
            const float GI2 = 1.f / r2v;
            const float GI3 = GI2 / S2;
            const float d3_r = 2.f * cr * S2;
            const float d3_th = 2.f * r2v * S * Cq;
            const float dd_rr = 2.f * S2;
            const float dd_rth = 4.f * cr * S * Cq;
            const float dd_thth = 2.f * r2v * (Cq * Cq - S2);

            auto fjsel = [&](int b) { return sel4(b, fja[pt][0], fja[pt][1], fja[pt][2], fja[pt][3]); };
            auto dgd = [&](int a, int b) {
                float v1 = E * fjsel(b);
                float v2 = (b == 1) ? (2.f * cr) : 0.f;
                float v3 = (b == 1) ? d3_r : ((b == 2) ? d3_th : 0.f);
                return (a == 1) ? v1 : ((a == 2) ? v2 : ((a == 3) ? v3 : 0.f));
            };
            auto d2f = [&](int a, int b, int l) {
                float v1 = E * (fjsel(b) * fjsel(l) + fkB[b * 4 + l]);
                float v2 = (b == 1 && l == 1) ? 2.f : 0.f;
                float v3 = (b == 1 && l == 1) ? dd_rr
                           : (((b == 1 && l == 2) || (b == 2 && l == 1)) ? dd_rth
                           : ((b == 2 && l == 2) ? dd_thth : 0.f));
                return (a == 1) ? v1 : ((a == 2) ? v2 : ((a == 3) ? v3 : 0.f));
            };

            const float GIi = sel4(li, -1.f, GI1, GI2, GI3);
            float P = (lk == li ? dgd(li, lj) : 0.f)
                    + (lj == li ? dgd(li, lk) : 0.f)
                    - (lj == lk ? dgd(lj, li) : 0.f);
            gmB[lane] = 0.5f * GIi * P;
            const float GIi2 = GIi * GIi;
            float Q0 = (lk == li ? d2f(li, lj, 0) : 0.f) + (lj == li ? d2f(li, lk, 0) : 0.f) - (lj == lk ? d2f(lj, li, 0) : 0.f);
            float Q1 = (lk == li ? d2f(li, lj, 1) : 0.f) + (lj == li ? d2f(li, lk, 1) : 0.f) - (lj == lk ? d2f(lj, li, 1) : 0.f);
            float Q2 = (lk == li ? d2f(li, lj, 2) : 0.f) + (lj == li ? d2f(li, lk, 2) : 0.f) - (lj == lk ? d2f(lj, li, 2) : 0.f);
            float Q3 = (lk == li ? d2f(li, lj, 3) : 0.f) + (lj == li ? d2f(li, lk, 3) : 0.f) - (lj == lk ? d2f(lj, li, 3) : 0.f);
            const float dgm0 = 0.5f * (GIi * Q0 - dgd(li, 0) * GIi2 * P);
            const float dgm1 = 0.5f * (GIi * Q1 - dgd(li, 1) * GIi2 * P);
            const float dgm2 = 0.5f * (GIi * Q2 - dgd(li, 2) * GIi2 * P);
            const float dgm3 = 0.5f * (GIi * Q3 - dgd(li, 3) * GIi2 * P);
            reinterpret_cast<float4*>(dgmB)[lane] = make_float4(dgm0, dgm1, dgm2, dgm3);
        }
        WAITLDS;

        // ---------- merged Ricci contraction: lanes 0-15 -> pt0, 16-31 -> pt1
        if (lane < 32) {
            float* cp = cb + pt16 * 512;
            const float* gmB = cp;
            const float* dgmB = cp + 64;
            float* rcB = cp + 320;
            const int j = sub >> 2, k = sub & 3;
            float T0 = 0, T1 = 0, T2 = 0, T3 = 0;
            #pragma unroll
            for (int i = 0; i < 4; ++i) {
                T0 += gmB[i * 16 + 0 + i];
                T1 += gmB[i * 16 + 4 + i];
                T2 += gmB[i * 16 + 8 + i];
                T3 += gmB[i * 16 + 12 + i];
            }
            float t1 = gmB[0 + j * 4 + k] * T0 + gmB[16 + j * 4 + k] * T1
                     + gmB[32 + j * 4 + k] * T2 + gmB[48 + j * 4 + k] * T3;
            float t2 = 0.f;
            #pragma unroll
            for (int m = 0; m < 4; ++m)
                #pragma unroll
                for (int i = 0; i < 4; ++i)
                    t2 += gmB[m * 16 + j * 4 + i] * gmB[i * 16 + m * 4 + k];
            float t3 = 0.f, t4 = 0.f;
            #pragma unroll
            for (int i = 0; i < 4; ++i) {
                t3 += dgmB[(i * 16 + j * 4 + k) * 4 + i];
                t4 += dgmB[(i * 16 + j * 4 + i) * 4 + k];
            }
            rcB[sub] = t1 - t2 + t3 - t4;
        }
        WAITLDS;

        // ---------- merged Einstein assembly + store: lanes 0-31
        if (lane < 32) {
            const float* cp = cb + pt16 * 512;
            const float* rcB = cp + 320;
            const float cr = pt16 ? c4[1].y : c4[0].y;
            const float cth = pt16 ? c4[1].z : c4[0].z;
            const float fvp = pt16 ? fv[1] : fv[0];
            float S, Cq;
            __sincosf(cth, &S, &Cq);
            const float E = __expf(fvp);
            const float GI1 = 1.f / E;
            const float GI2 = 1.f / (cr * cr);
            const float GI3 = GI2 / (S * S);
            const int j = sub >> 2, k = sub & 3;
            const float R = -rcB[0] + GI1 * rcB[5] + GI2 * rcB[10] + GI3 * rcB[15];
            const float GIj = sel4(j, -1.f, GI1, GI2, GI3);
            const float GIk = sel4(k, -1.f, GI1, GI2, GI3);
            const float o = GIj * GIk * rcB[sub] - ((j == k) ? 0.5f * R * GIj : 0.f);
            out[(p + pt16) * 16 + sub] = o;
        }
        WAITLDS;
    }
}

extern "C" void kernel_launch(void* const* d_in, const int* in_sizes, int n_in,
                              void* d_out, int out_size, void* d_ws, size_t ws_size,
                              hipStream_t stream) {
    const float* coords = (const float*)d_in[0];
    const float* W1 = (const float*)d_in[1];
    const float* b1 = (const float*)d_in[2];
    const float* W2 = (const float*)d_in[3];
    const float* b2 = (const float*)d_in[4];
    const float* W3 = (const float*)d_in[5];
    const float* b3 = (const float*)d_in[6];
    const float* W4 = (const float*)d_in[7];
    const float* b4 = (const float*)d_in[8];
    const int B = in_sizes[0] / 4;

    hipLaunchKernelGGL(einstein_kernel, dim3(NBLOCKS), dim3(BLOCK), 0, stream,
                       coords, W1, b1, W2, b2, W3, b3, W4, b4,
                       (float*)d_out, B);
}

// Round 12
// 91.357 us; speedup vs baseline: 3.3804x; 1.0398x over previous
//
#include <hip/hip_runtime.h>

#define NBLOCKS 4096
#define WPB 4
#define BLOCK 256

typedef __attribute__((ext_vector_type(8))) short sh8;
typedef __attribute__((ext_vector_type(4))) float f32x4;

__device__ __forceinline__ float sel4(int b, float x0, float x1, float x2, float x3) {
    float r = x3;
    r = (b == 2) ? x2 : r;
    r = (b == 1) ? x1 : r;
    r = (b == 0) ? x0 : r;
    return r;
}

__device__ __forceinline__ float frcp(float x) { return __builtin_amdgcn_rcpf(x); }

__device__ __forceinline__ float fast_tanh(float x) {
    // tanh = 1 - 2*rcp(exp(2x)+1); raw v_rcp_f32 (~1 ulp) vs 10-op div sequence
    float e = __expf(2.f * x);
    return 1.f - 2.f * frcp(e + 1.f);
}

// swizzled bf16 index into a [rows][64] LDS array (row stride = 32 dwords).
__device__ __forceinline__ int zidx(int m, int u) {
    return (((m << 5) + (((u >> 1) ^ ((m & 7) << 2)))) << 1) + (u & 1);
}

// load an 8x-bf16 MFMA fragment: row = matrix row, lanes' k-slice = kt*32 + g*8
__device__ __forceinline__ sh8 ldfrag(const unsigned short* base, int row, int g, int kt) {
    const int dw = (row << 5) + ((((kt << 4) + (g << 2))) ^ ((row & 7) << 2));
    return *(const sh8*)(base + (dw << 1));
}

// round-to-nearest-even bf16 (host-free path, used in preamble staging)
__device__ __forceinline__ unsigned short rtn_bf16(float x) {
    unsigned u = __float_as_uint(x);
    u += 0x7FFFu + ((u >> 16) & 1u);
    return (unsigned short)(u >> 16);
}

// packed f32->bf16 RNE convert: dst = bf16(lo) | bf16(hi)<<16  (1 VALU op)
__device__ __forceinline__ unsigned cvt_pk_bf16(float lo, float hi) {
    unsigned r;
    asm("v_cvt_pk_bf16_f32 %0, %1, %2" : "=v"(r) : "v"(lo), "v"(hi));
    return r;
}

// split f32 into truncated-bf16 hi and bf16(x-hi) lo  (used for W4 only)
__device__ __forceinline__ void wsplit(float x, unsigned short& h, unsigned short& l) {
    const unsigned ub = __float_as_uint(x);
    const unsigned hb = ub & 0xffff0000u;
    const float lf = x - __uint_as_float(hb);
    h = (unsigned short)(hb >> 16);
    l = (unsigned short)(__float_as_uint(lf) >> 16);
}

// stage 15 jet values as bf16 via cvt_pk pairs: 15 VALU + 15 ds_write_b16
// (was ~45 VALU with hand-RTN)
__device__ __forceinline__ void stage15s(unsigned short* zh, const float* z, int lane) {
    #pragma unroll
    for (int m = 0; m < 14; m += 2) {
        const unsigned r = cvt_pk_bf16(z[m], z[m + 1]);
        zh[zidx(m, lane)] = (unsigned short)r;
        zh[zidx(m + 1, lane)] = (unsigned short)(r >> 16);
    }
    zh[zidx(14, lane)] = (unsigned short)cvt_pk_bf16(z[14], z[14]);
}

__device__ __forceinline__ void jet_nl(const float* a, float bias, float* z) {
    const float a0v = a[0] + bias;
    const float y = fast_tanh(a0v);
    const float D = 1.f - y * y;
    const float m2 = -2.f * y * D;
    z[0] = y;
    z[1] = D * a[1]; z[2] = D * a[2]; z[3] = D * a[3]; z[4] = D * a[4];
    z[5] = D * a[5] + m2 * a[1] * a[1];
    z[6] = D * a[6] + m2 * a[1] * a[2];
    z[7] = D * a[7] + m2 * a[1] * a[3];
    z[8] = D * a[8] + m2 * a[1] * a[4];
    z[9] = D * a[9] + m2 * a[2] * a[2];
    z[10] = D * a[10] + m2 * a[2] * a[3];
    z[11] = D * a[11] + m2 * a[2] * a[4];
    z[12] = D * a[12] + m2 * a[3] * a[3];
    z[13] = D * a[13] + m2 * a[3] * a[4];
    z[14] = D * a[14] + m2 * a[4] * a[4];
}

// compiler-only reordering fence (R10: full lgkmcnt(0) drains were neutral;
// same-wave DS is in-order, so ordering at IR level suffices)
#define WAITLDS asm volatile("" ::: "memory")

// PRECISION LEDGER: state/W2/W3 = single RNE bf16; W1 = f32; W4 = hi/lo bf16.
// absmax = 6144 vs threshold 1.024e4 (1.67x headroom) -- NO further precision
// cuts. rcpf / cvt_pk changes are ~1ulp f32, invisible at this error scale.
// REGISTER HISTORY: (256,5)->930MB scratch; (256,4) Whf-struct -> 56MB;
// this struct needs ~60-75 regs -> (256,4) cap 128 is safe.
__global__ __launch_bounds__(BLOCK, 4) void einstein_kernel(
    const float* __restrict__ coords,
    const float* __restrict__ gW1, const float* __restrict__ gb1,
    const float* __restrict__ gW2, const float* __restrict__ gb2,
    const float* __restrict__ gW3, const float* __restrict__ gb3,
    const float* __restrict__ gW4, const float* __restrict__ gb4,
    float* __restrict__ out, int B)
{
    __shared__ __align__(16) unsigned short wlds[2][4096];
    __shared__ __align__(16) unsigned short w4lds[2048];
    __shared__ __align__(16) unsigned short zS[WPB][2048];

    const int wv = threadIdx.x >> 6;
    const int lane = threadIdx.x & 63;
    const int n15 = lane & 15;
    const int g = lane >> 4;

    unsigned short* zbase = zS[wv];
    float* cb = (float*)zbase;

    // ---- stage W2/W3 as single RNE bf16 (swizzled, transposed) ----
    for (int e = threadIdx.x; e < 4096; e += BLOCK) {
        const int o = e & 63, i = e >> 6;
        const int ix = zidx(o, i);
        wlds[0][ix] = rtn_bf16(gW2[i * 64 + o]);
        wlds[1][ix] = rtn_bf16(gW3[i * 64 + o]);
    }
    // W4 B-fragments (col 0 = W4, cols 1-15 zero), hi/lo
    #pragma unroll
    for (int kt = 0; kt < 2; ++kt) {
        sh8 bh, bl;
        #pragma unroll
        for (int e = 0; e < 8; ++e) {
            const float v = (n15 == 0) ? gW4[kt * 32 + g * 8 + e] : 0.f;
            unsigned short h, l;
            wsplit(v, h, l);
            bh[e] = (short)h;
            bl[e] = (short)l;
        }
        *(sh8*)(w4lds + kt * 512 + (lane << 3)) = bh;
        *(sh8*)(w4lds + (2 + kt) * 512 + (lane << 3)) = bl;
    }
    __syncthreads();
    // A-row 15 garbage (cb alias residue) is confined to C row 15: never read.

    // per-lane layer-1 constants (lane = hidden unit)
    const float w1c0 = gW1[0 * 64 + lane];
    const float w1c1 = gW1[1 * 64 + lane];
    const float w1c2 = gW1[2 * 64 + lane];
    const float w1c3 = gW1[3 * 64 + lane];
    const float b1c = gb1[lane], b2c = gb2[lane], b3c = gb3[lane];
    const float b4v = gb4[0];

    const int wid = blockIdx.x * WPB + wv;
    const int nw = NBLOCKS * WPB;

    for (int p = 2 * wid; p < B; p += 2 * nw) {
        float4 c4[2];
        c4[0] = reinterpret_cast<const float4*>(coords)[p];
        c4[1] = reinterpret_cast<const float4*>(coords)[p + 1];

        // ---------- layer 1 (4 -> 64), closed-form jet, lane = unit; both points
        #pragma unroll
        for (int pt = 0; pt < 2; ++pt) {
            float z[15];
            const float u = b1c + c4[pt].x * w1c0 + c4[pt].y * w1c1 + c4[pt].z * w1c2 + c4[pt].w * w1c3;
            const float y = fast_tanh(u);
            const float D = 1.f - y * y;
            const float m2 = -2.f * y * D;
            z[0] = y;
            z[1] = D * w1c0; z[2] = D * w1c1; z[3] = D * w1c2; z[4] = D * w1c3;
            z[5] = m2 * w1c0 * w1c0; z[6] = m2 * w1c0 * w1c1; z[7] = m2 * w1c0 * w1c2; z[8] = m2 * w1c0 * w1c3;
            z[9] = m2 * w1c1 * w1c1; z[10] = m2 * w1c1 * w1c2; z[11] = m2 * w1c1 * w1c3;
            z[12] = m2 * w1c2 * w1c2; z[13] = m2 * w1c2 * w1c3; z[14] = m2 * w1c3 * w1c3;
            stage15s(zbase + pt * 1024, z, lane);
        }
        WAITLDS;

        // ---------- layers 2,3: jet-GEMM on MFMA, single-bf16 A and B
        #pragma unroll
        for (int LL = 0; LL < 2; ++LL) {
            const unsigned short* wl = wlds[LL];
            sh8 A0[2], A1[2];
            #pragma unroll
            for (int pt = 0; pt < 2; ++pt) {
                A0[pt] = ldfrag(zbase + pt * 1024, n15, g, 0);
                A1[pt] = ldfrag(zbase + pt * 1024, n15, g, 1);
            }
            WAITLDS;   // frag reads ordered before scatter clobbers the alias
            f32x4 acc[2][4];
            #pragma unroll
            for (int nt = 0; nt < 4; ++nt) {
                const sh8 B0 = ldfrag(wl, nt * 16 + n15, g, 0);
                const sh8 B1 = ldfrag(wl, nt * 16 + n15, g, 1);
                #pragma unroll
                for (int pt = 0; pt < 2; ++pt) {
                    f32x4 a0 = {0.f, 0.f, 0.f, 0.f};
                    a0 = __builtin_amdgcn_mfma_f32_16x16x32_bf16(A0[pt], B0, a0, 0, 0, 0);
                    a0 = __builtin_amdgcn_mfma_f32_16x16x32_bf16(A1[pt], B1, a0, 0, 0, 0);
                    acc[pt][nt] = a0;
                }
            }
            // serialized per-pt transpose through the shared 4 KB cb
            float z0[15], z1[15];
            {
                #pragma unroll
                for (int nt = 0; nt < 4; ++nt) {
                    const int u = nt * 16 + n15;
                    *(f32x4*)(cb + u * 16 + ((g << 2) ^ (u & 12))) = acc[0][nt];
                }
                WAITLDS;
                float a[15];
                #pragma unroll
                for (int c = 0; c < 4; ++c) {
                    const f32x4 r = *(const f32x4*)(cb + lane * 16 + ((c << 2) ^ (lane & 12)));
                    #pragma unroll
                    for (int t = 0; t < 4; ++t)
                        if (c * 4 + t < 15) a[c * 4 + t] = r[t];
                }
                WAITLDS;   // pt0 gather ordered before pt1 scatter
                jet_nl(a, LL ? b3c : b2c, z0);
            }
            {
                #pragma unroll
                for (int nt = 0; nt < 4; ++nt) {
                    const int u = nt * 16 + n15;
                    *(f32x4*)(cb + u * 16 + ((g << 2) ^ (u & 12))) = acc[1][nt];
                }
                WAITLDS;
                float a[15];
                #pragma unroll
                for (int c = 0; c < 4; ++c) {
                    const f32x4 r = *(const f32x4*)(cb + lane * 16 + ((c << 2) ^ (lane & 12)));
                    #pragma unroll
                    for (int t = 0; t < 4; ++t)
                        if (c * 4 + t < 15) a[c * 4 + t] = r[t];
                }
                WAITLDS;   // pt1 gather ordered before restage clobbers
                jet_nl(a, LL ? b3c : b2c, z1);
            }
            stage15s(zbase, z0, lane);
            stage15s(zbase + 1024, z1, lane);
            WAITLDS;
        }

        // ---------- final layer (64 -> 1) as MFMA reduce, W4 hi/lo
        {
            const sh8 Bh0 = *(const sh8*)(w4lds + 0 * 512 + (lane << 3));
            const sh8 Bh1 = *(const sh8*)(w4lds + 1 * 512 + (lane << 3));
            const sh8 Bw0 = *(const sh8*)(w4lds + 2 * 512 + (lane << 3));
            const sh8 Bw1 = *(const sh8*)(w4lds + 3 * 512 + (lane << 3));
            f32x4 rs[2];
            #pragma unroll
            for (int pt = 0; pt < 2; ++pt) {
                const sh8 A0 = ldfrag(zbase + pt * 1024, n15, g, 0);
                const sh8 A1 = ldfrag(zbase + pt * 1024, n15, g, 1);
                f32x4 r = {0.f, 0.f, 0.f, 0.f};
                r = __builtin_amdgcn_mfma_f32_16x16x32_bf16(A0, Bh0, r, 0, 0, 0);
                r = __builtin_amdgcn_mfma_f32_16x16x32_bf16(A1, Bh1, r, 0, 0, 0);
                r = __builtin_amdgcn_mfma_f32_16x16x32_bf16(A0, Bw0, r, 0, 0, 0);
                r = __builtin_amdgcn_mfma_f32_16x16x32_bf16(A1, Bw1, r, 0, 0, 0);
                rs[pt] = r;
            }
            WAITLDS;   // frag reads ordered before col-0 writes
            if (n15 == 0) {
                *(f32x4*)(cb + (g << 2)) = rs[0];
                *(f32x4*)(cb + 512 + (g << 2)) = rs[1];
            }
        }
        WAITLDS;
        float fv[2], fja[2][4], sv[2][10];
        #pragma unroll
        for (int pt = 0; pt < 2; ++pt) {
            const float* cp = cb + pt * 512;
            const f32x4 r0 = *(const f32x4*)(cp);
            const f32x4 r1 = *(const f32x4*)(cp + 4);
            const f32x4 r2 = *(const f32x4*)(cp + 8);
            const f32x4 r3 = *(const f32x4*)(cp + 12);
            fv[pt] = r0[0] + b4v;
            fja[pt][0] = r0[1]; fja[pt][1] = r0[2]; fja[pt][2] = r0[3]; fja[pt][3] = r1[0];
            sv[pt][0] = r1[1]; sv[pt][1] = r1[2]; sv[pt][2] = r1[3];
            sv[pt][3] = r2[0]; sv[pt][4] = r2[1]; sv[pt][5] = r2[2]; sv[pt][6] = r2[3];
            sv[pt][7] = r3[0]; sv[pt][8] = r3[1]; sv[pt][9] = r3[2];
        }
        WAITLDS;

        // ---------- per-pt metric scalars computed ONCE into registers
        float Ev[2], GI1v[2], GI2v[2], GI3v[2], Sv[2], Cv[2];
        #pragma unroll
        for (int pt = 0; pt < 2; ++pt) {
            __sincosf(c4[pt].z, &Sv[pt], &Cv[pt]);
            Ev[pt] = __expf(fv[pt]);
            GI1v[pt] = frcp(Ev[pt]);
            GI2v[pt] = frcp(c4[pt].y * c4[pt].y);
            GI3v[pt] = GI2v[pt] * frcp(Sv[pt] * Sv[pt]);
        }

        // ---------- merged Hessian staging: lanes 0-15 -> pt0, 16-31 -> pt1
        const int pt16 = (lane >> 4) & 1;
        const int sub = lane & 15;
        if (lane < 32) {
            float* fkB = cb + pt16 * 512 + 336;
            const int jj = sub >> 2, kk = sub & 3;
            const int lo = jj < kk ? jj : kk, hi = jj < kk ? kk : jj;
            const int code = lo * 4 + hi;
            const float p0 = pt16 ? sv[1][0] : sv[0][0];
            const float p1 = pt16 ? sv[1][1] : sv[0][1];
            const float p2 = pt16 ? sv[1][2] : sv[0][2];
            const float p3 = pt16 ? sv[1][3] : sv[0][3];
            const float p4 = pt16 ? sv[1][4] : sv[0][4];
            const float p5 = pt16 ? sv[1][5] : sv[0][5];
            const float p6 = pt16 ? sv[1][6] : sv[0][6];
            const float p7 = pt16 ? sv[1][7] : sv[0][7];
            const float p8 = pt16 ? sv[1][8] : sv[0][8];
            const float p9 = pt16 ? sv[1][9] : sv[0][9];
            float v = p9;
            v = code == 0 ? p0 : v;  v = code == 1 ? p1 : v;  v = code == 2 ? p2 : v;
            v = code == 3 ? p3 : v;  v = code == 5 ? p4 : v;  v = code == 6 ? p5 : v;
            v = code == 7 ? p6 : v;  v = code == 10 ? p7 : v; v = code == 11 ? p8 : v;
            fkB[sub] = v;
        }
        WAITLDS;

        // ---------- Christoffel + derivatives: full width, per-pt unrolled
        const int li = (lane >> 4) & 3, lk = (lane >> 2) & 3, lj = lane & 3;
        #pragma unroll
        for (int pt = 0; pt < 2; ++pt) {
            float* cp = cb + pt * 512;
            float* gmB = cp;
            float* dgmB = cp + 64;
            const float* fkB = cp + 336;
            const float cr = c4[pt].y;
            const float S = Sv[pt], Cq = Cv[pt];
            const float E = Ev[pt];
            const float r2v = cr * cr, S2 = S * S;
            const float GI1 = GI1v[pt];
            const float GI2 = GI2v[pt];
            const float GI3 = GI3v[pt];
            const float d3_r = 2.f * cr * S2;
            const float d3_th = 2.f * r2v * S * Cq;
            const float dd_rr = 2.f * S2;
            const float dd_rth = 4.f * cr * S * Cq;
            const float dd_thth = 2.f * r2v * (Cq * Cq - S2);

            auto fjsel = [&](int b) { return sel4(b, fja[pt][0], fja[pt][1], fja[pt][2], fja[pt][3]); };
            auto dgd = [&](int a, int b) {
                float v1 = E * fjsel(b);
                float v2 = (b == 1) ? (2.f * cr) : 0.f;
                float v3 = (b == 1) ? d3_r : ((b == 2) ? d3_th : 0.f);
                return (a == 1) ? v1 : ((a == 2) ? v2 : ((a == 3) ? v3 : 0.f));
            };
            auto d2f = [&](int a, int b, int l) {
                float v1 = E * (fjsel(b) * fjsel(l) + fkB[b * 4 + l]);
                float v2 = (b == 1 && l == 1) ? 2.f : 0.f;
                float v3 = (b == 1 && l == 1) ? dd_rr
                           : (((b == 1 && l == 2) || (b == 2 && l == 1)) ? dd_rth
                           : ((b == 2 && l == 2) ? dd_thth : 0.f));
                return (a == 1) ? v1 : ((a == 2) ? v2 : ((a == 3) ? v3 : 0.f));
            };

            const float GIi = sel4(li, -1.f, GI1, GI2, GI3);
            float P = (lk == li ? dgd(li, lj) : 0.f)
                    + (lj == li ? dgd(li, lk) : 0.f)
                    - (lj == lk ? dgd(lj, li) : 0.f);
            gmB[lane] = 0.5f * GIi * P;
            const float GIi2 = GIi * GIi;
            float Q0 = (lk == li ? d2f(li, lj, 0) : 0.f) + (lj == li ? d2f(li, lk, 0) : 0.f) - (lj == lk ? d2f(lj, li, 0) : 0.f);
            float Q1 = (lk == li ? d2f(li, lj, 1) : 0.f) + (lj == li ? d2f(li, lk, 1) : 0.f) - (lj == lk ? d2f(lj, li, 1) : 0.f);
            float Q2 = (lk == li ? d2f(li, lj, 2) : 0.f) + (lj == li ? d2f(li, lk, 2) : 0.f) - (lj == lk ? d2f(lj, li, 2) : 0.f);
            float Q3 = (lk == li ? d2f(li, lj, 3) : 0.f) + (lj == li ? d2f(li, lk, 3) : 0.f) - (lj == lk ? d2f(lj, li, 3) : 0.f);
            const float dgm0 = 0.5f * (GIi * Q0 - dgd(li, 0) * GIi2 * P);
            const float dgm1 = 0.5f * (GIi * Q1 - dgd(li, 1) * GIi2 * P);
            const float dgm2 = 0.5f * (GIi * Q2 - dgd(li, 2) * GIi2 * P);
            const float dgm3 = 0.5f * (GIi * Q3 - dgd(li, 3) * GIi2 * P);
            reinterpret_cast<float4*>(dgmB)[lane] = make_float4(dgm0, dgm1, dgm2, dgm3);
        }
        WAITLDS;

        // ---------- merged Ricci contraction: lanes 0-15 -> pt0, 16-31 -> pt1
        if (lane < 32) {
            float* cp = cb + pt16 * 512;
            const float* gmB = cp;
            const float* dgmB = cp + 64;
            float* rcB = cp + 320;
            const int j = sub >> 2, k = sub & 3;
            float T0 = 0, T1 = 0, T2 = 0, T3 = 0;
            #pragma unroll
            for (int i = 0; i < 4; ++i) {
                T0 += gmB[i * 16 + 0 + i];
                T1 += gmB[i * 16 + 4 + i];
                T2 += gmB[i * 16 + 8 + i];
                T3 += gmB[i * 16 + 12 + i];
            }
            float t1 = gmB[0 + j * 4 + k] * T0 + gmB[16 + j * 4 + k] * T1
                     + gmB[32 + j * 4 + k] * T2 + gmB[48 + j * 4 + k] * T3;
            float t2 = 0.f;
            #pragma unroll
            for (int m = 0; m < 4; ++m)
                #pragma unroll
                for (int i = 0; i < 4; ++i)
                    t2 += gmB[m * 16 + j * 4 + i] * gmB[i * 16 + m * 4 + k];
            float t3 = 0.f, t4 = 0.f;
            #pragma unroll
            for (int i = 0; i < 4; ++i) {
                t3 += dgmB[(i * 16 + j * 4 + k) * 4 + i];
                t4 += dgmB[(i * 16 + j * 4 + i) * 4 + k];
            }
            rcB[sub] = t1 - t2 + t3 - t4;
        }
        WAITLDS;

        // ---------- merged Einstein assembly + store: lanes 0-31
        if (lane < 32) {
            const float* cp = cb + pt16 * 512;
            const float* rcB = cp + 320;
            const float GI1 = pt16 ? GI1v[1] : GI1v[0];
            const float GI2 = pt16 ? GI2v[1] : GI2v[0];
            const float GI3 = pt16 ? GI3v[1] : GI3v[0];
            const int j = sub >> 2, k = sub & 3;
            const float R = -rcB[0] + GI1 * rcB[5] + GI2 * rcB[10] + GI3 * rcB[15];
            const float GIj = sel4(j, -1.f, GI1, GI2, GI3);
            const float GIk = sel4(k, -1.f, GI1, GI2, GI3);
            const float o = GIj * GIk * rcB[sub] - ((j == k) ? 0.5f * R * GIj : 0.f);
            out[(p + pt16) * 16 + sub] = o;
        }
        WAITLDS;
    }
}

extern "C" void kernel_launch(void* const* d_in, const int* in_sizes, int n_in,
                              void* d_out, int out_size, void* d_ws, size_t ws_size,
                              hipStream_t stream) {
    const float* coords = (const float*)d_in[0];
    const float* W1 = (const float*)d_in[1];
    const float* b1 = (const float*)d_in[2];
    const float* W2 = (const float*)d_in[3];
    const float* b2 = (const float*)d_in[4];
    const float* W3 = (const float*)d_in[5];
    const float* b3 = (const float*)d_in[6];
    const float* W4 = (const float*)d_in[7];
    const float* b4 = (const float*)d_in[8];
    const int B = in_sizes[0] / 4;

    hipLaunchKernelGGL(einstein_kernel, dim3(NBLOCKS), dim3(BLOCK), 0, stream,
                       coords, W1, b1, W2, b2, W3, b3, W4, b4,
                       (float*)d_out, B);
}

// Round 13
// 72.025 us; speedup vs baseline: 4.2877x; 1.2684x over previous
//
#include <hip/hip_runtime.h>

#define NBLOCKS 4096
#define WPB 4
#define BLOCK 256

typedef __attribute__((ext_vector_type(8))) short sh8;
typedef __attribute__((ext_vector_type(4))) float f32x4;

__device__ __forceinline__ float frcp(float x) { return __builtin_amdgcn_rcpf(x); }

__device__ __forceinline__ float fast_tanh(float x) {
    float e = __expf(2.f * x);
    return 1.f - 2.f * frcp(e + 1.f);
}

// swizzled bf16 index into a [rows][64] LDS array (row stride = 32 dwords).
__device__ __forceinline__ int zidx(int m, int u) {
    return (((m << 5) + (((u >> 1) ^ ((m & 7) << 2)))) << 1) + (u & 1);
}

__device__ __forceinline__ sh8 ldfrag(const unsigned short* base, int row, int g, int kt) {
    const int dw = (row << 5) + ((((kt << 4) + (g << 2))) ^ ((row & 7) << 2));
    return *(const sh8*)(base + (dw << 1));
}

__device__ __forceinline__ unsigned short rtn_bf16(float x) {
    unsigned u = __float_as_uint(x);
    u += 0x7FFFu + ((u >> 16) & 1u);
    return (unsigned short)(u >> 16);
}

__device__ __forceinline__ unsigned cvt_pk_bf16(float lo, float hi) {
    unsigned r;
    asm("v_cvt_pk_bf16_f32 %0, %1, %2" : "=v"(r) : "v"(lo), "v"(hi));
    return r;
}

__device__ __forceinline__ void wsplit(float x, unsigned short& h, unsigned short& l) {
    const unsigned ub = __float_as_uint(x);
    const unsigned hb = ub & 0xffff0000u;
    const float lf = x - __uint_as_float(hb);
    h = (unsigned short)(hb >> 16);
    l = (unsigned short)(__float_as_uint(lf) >> 16);
}

__device__ __forceinline__ void stage15s(unsigned short* zh, const float* z, int lane) {
    #pragma unroll
    for (int m = 0; m < 14; m += 2) {
        const unsigned r = cvt_pk_bf16(z[m], z[m + 1]);
        zh[zidx(m, lane)] = (unsigned short)r;
        zh[zidx(m + 1, lane)] = (unsigned short)(r >> 16);
    }
    zh[zidx(14, lane)] = (unsigned short)cvt_pk_bf16(z[14], z[14]);
}

__device__ __forceinline__ void jet_nl(const float* a, float bias, float* z) {
    const float a0v = a[0] + bias;
    const float y = fast_tanh(a0v);
    const float D = 1.f - y * y;
    const float m2 = -2.f * y * D;
    z[0] = y;
    z[1] = D * a[1]; z[2] = D * a[2]; z[3] = D * a[3]; z[4] = D * a[4];
    z[5] = D * a[5] + m2 * a[1] * a[1];
    z[6] = D * a[6] + m2 * a[1] * a[2];
    z[7] = D * a[7] + m2 * a[1] * a[3];
    z[8] = D * a[8] + m2 * a[1] * a[4];
    z[9] = D * a[9] + m2 * a[2] * a[2];
    z[10] = D * a[10] + m2 * a[2] * a[3];
    z[11] = D * a[11] + m2 * a[2] * a[4];
    z[12] = D * a[12] + m2 * a[3] * a[3];
    z[13] = D * a[13] + m2 * a[3] * a[4];
    z[14] = D * a[14] + m2 * a[4] * a[4];
}

#define WAITLDS asm volatile("" ::: "memory")

// ============ kernel 1: MLP jet pipeline -> 15 scalars/pt into ws ============
// PRECISION LEDGER: state/W2/W3 = single RNE bf16; W1 = f32; W4 = hi/lo bf16.
// absmax 6144 vs threshold 1.024e4 -- no further precision cuts.
__global__ __launch_bounds__(BLOCK, 4) void jet_kernel(
    const float* __restrict__ coords,
    const float* __restrict__ gW1, const float* __restrict__ gb1,
    const float* __restrict__ gW2, const float* __restrict__ gb2,
    const float* __restrict__ gW3, const float* __restrict__ gb3,
    const float* __restrict__ gW4,
    float* __restrict__ ws, int B)
{
    __shared__ __align__(16) unsigned short wlds[2][4096];
    __shared__ __align__(16) unsigned short w4lds[2048];
    __shared__ __align__(16) unsigned short zS[WPB][2048];

    const int wv = threadIdx.x >> 6;
    const int lane = threadIdx.x & 63;
    const int n15 = lane & 15;
    const int g = lane >> 4;

    unsigned short* zbase = zS[wv];
    float* cb = (float*)zbase;

    for (int e = threadIdx.x; e < 4096; e += BLOCK) {
        const int o = e & 63, i = e >> 6;
        const int ix = zidx(o, i);
        wlds[0][ix] = rtn_bf16(gW2[i * 64 + o]);
        wlds[1][ix] = rtn_bf16(gW3[i * 64 + o]);
    }
    #pragma unroll
    for (int kt = 0; kt < 2; ++kt) {
        sh8 bh, bl;
        #pragma unroll
        for (int e = 0; e < 8; ++e) {
            const float v = (n15 == 0) ? gW4[kt * 32 + g * 8 + e] : 0.f;
            unsigned short h, l;
            wsplit(v, h, l);
            bh[e] = (short)h;
            bl[e] = (short)l;
        }
        *(sh8*)(w4lds + kt * 512 + (lane << 3)) = bh;
        *(sh8*)(w4lds + (2 + kt) * 512 + (lane << 3)) = bl;
    }
    __syncthreads();
    // A-row 15 garbage (cb alias residue) confined to C row 15: never read.

    const float w1c0 = gW1[0 * 64 + lane];
    const float w1c1 = gW1[1 * 64 + lane];
    const float w1c2 = gW1[2 * 64 + lane];
    const float w1c3 = gW1[3 * 64 + lane];
    const float b1c = gb1[lane], b2c = gb2[lane], b3c = gb3[lane];

    const int wid = blockIdx.x * WPB + wv;
    const int nw = NBLOCKS * WPB;

    for (int p = 2 * wid; p < B; p += 2 * nw) {
        float4 c4[2];
        c4[0] = reinterpret_cast<const float4*>(coords)[p];
        c4[1] = reinterpret_cast<const float4*>(coords)[p + 1];

        #pragma unroll
        for (int pt = 0; pt < 2; ++pt) {
            float z[15];
            const float u = b1c + c4[pt].x * w1c0 + c4[pt].y * w1c1 + c4[pt].z * w1c2 + c4[pt].w * w1c3;
            const float y = fast_tanh(u);
            const float D = 1.f - y * y;
            const float m2 = -2.f * y * D;
            z[0] = y;
            z[1] = D * w1c0; z[2] = D * w1c1; z[3] = D * w1c2; z[4] = D * w1c3;
            z[5] = m2 * w1c0 * w1c0; z[6] = m2 * w1c0 * w1c1; z[7] = m2 * w1c0 * w1c2; z[8] = m2 * w1c0 * w1c3;
            z[9] = m2 * w1c1 * w1c1; z[10] = m2 * w1c1 * w1c2; z[11] = m2 * w1c1 * w1c3;
            z[12] = m2 * w1c2 * w1c2; z[13] = m2 * w1c2 * w1c3; z[14] = m2 * w1c3 * w1c3;
            stage15s(zbase + pt * 1024, z, lane);
        }
        WAITLDS;

        #pragma unroll
        for (int LL = 0; LL < 2; ++LL) {
            const unsigned short* wl = wlds[LL];
            sh8 A0[2], A1[2];
            #pragma unroll
            for (int pt = 0; pt < 2; ++pt) {
                A0[pt] = ldfrag(zbase + pt * 1024, n15, g, 0);
                A1[pt] = ldfrag(zbase + pt * 1024, n15, g, 1);
            }
            WAITLDS;
            f32x4 acc[2][4];
            #pragma unroll
            for (int nt = 0; nt < 4; ++nt) {
                const sh8 B0 = ldfrag(wl, nt * 16 + n15, g, 0);
                const sh8 B1 = ldfrag(wl, nt * 16 + n15, g, 1);
                #pragma unroll
                for (int pt = 0; pt < 2; ++pt) {
                    f32x4 a0 = {0.f, 0.f, 0.f, 0.f};
                    a0 = __builtin_amdgcn_mfma_f32_16x16x32_bf16(A0[pt], B0, a0, 0, 0, 0);
                    a0 = __builtin_amdgcn_mfma_f32_16x16x32_bf16(A1[pt], B1, a0, 0, 0, 0);
                    acc[pt][nt] = a0;
                }
            }
            float z0[15], z1[15];
            {
                #pragma unroll
                for (int nt = 0; nt < 4; ++nt) {
                    const int u = nt * 16 + n15;
                    *(f32x4*)(cb + u * 16 + ((g << 2) ^ (u & 12))) = acc[0][nt];
                }
                WAITLDS;
                float a[15];
                #pragma unroll
                for (int c = 0; c < 4; ++c) {
                    const f32x4 r = *(const f32x4*)(cb + lane * 16 + ((c << 2) ^ (lane & 12)));
                    #pragma unroll
                    for (int t = 0; t < 4; ++t)
                        if (c * 4 + t < 15) a[c * 4 + t] = r[t];
                }
                WAITLDS;
                jet_nl(a, LL ? b3c : b2c, z0);
            }
            {
                #pragma unroll
                for (int nt = 0; nt < 4; ++nt) {
                    const int u = nt * 16 + n15;
                    *(f32x4*)(cb + u * 16 + ((g << 2) ^ (u & 12))) = acc[1][nt];
                }
                WAITLDS;
                float a[15];
                #pragma unroll
                for (int c = 0; c < 4; ++c) {
                    const f32x4 r = *(const f32x4*)(cb + lane * 16 + ((c << 2) ^ (lane & 12)));
                    #pragma unroll
                    for (int t = 0; t < 4; ++t)
                        if (c * 4 + t < 15) a[c * 4 + t] = r[t];
                }
                WAITLDS;
                jet_nl(a, LL ? b3c : b2c, z1);
            }
            stage15s(zbase, z0, lane);
            stage15s(zbase + 1024, z1, lane);
            WAITLDS;
        }

        // final layer (64 -> 1) as MFMA reduce; jets land in lanes n15==0
        {
            const sh8 Bh0 = *(const sh8*)(w4lds + 0 * 512 + (lane << 3));
            const sh8 Bh1 = *(const sh8*)(w4lds + 1 * 512 + (lane << 3));
            const sh8 Bw0 = *(const sh8*)(w4lds + 2 * 512 + (lane << 3));
            const sh8 Bw1 = *(const sh8*)(w4lds + 3 * 512 + (lane << 3));
            #pragma unroll
            for (int pt = 0; pt < 2; ++pt) {
                const sh8 A0 = ldfrag(zbase + pt * 1024, n15, g, 0);
                const sh8 A1 = ldfrag(zbase + pt * 1024, n15, g, 1);
                f32x4 r = {0.f, 0.f, 0.f, 0.f};
                r = __builtin_amdgcn_mfma_f32_16x16x32_bf16(A0, Bh0, r, 0, 0, 0);
                r = __builtin_amdgcn_mfma_f32_16x16x32_bf16(A1, Bh1, r, 0, 0, 0);
                r = __builtin_amdgcn_mfma_f32_16x16x32_bf16(A0, Bw0, r, 0, 0, 0);
                r = __builtin_amdgcn_mfma_f32_16x16x32_bf16(A1, Bw1, r, 0, 0, 0);
                // row m = g*4+reg, col 0 = lanes n15==0: 4 lanes store 4 jets each
                if (n15 == 0)
                    reinterpret_cast<f32x4*>(ws)[(p + pt) * 4 + g] = r;
            }
        }
        WAITLDS;   // frag reads ordered before next iteration's stage15s clobbers
    }
}

// ============ kernel 2: per-point Einstein epilogue, all-register ============
__global__ void einstein_epilogue(
    const float* __restrict__ coords,
    const float* __restrict__ ws,
    const float* __restrict__ gb4,
    float* __restrict__ out, int B)
{
    const int p = blockIdx.x * blockDim.x + threadIdx.x;
    if (p >= B) return;
    const float4 c4 = reinterpret_cast<const float4*>(coords)[p];
    const float cr = c4.y, cth = c4.z;
    const f32x4 r0 = reinterpret_cast<const f32x4*>(ws)[p * 4 + 0];
    const f32x4 r1 = reinterpret_cast<const f32x4*>(ws)[p * 4 + 1];
    const f32x4 r2 = reinterpret_cast<const f32x4*>(ws)[p * 4 + 2];
    const f32x4 r3 = reinterpret_cast<const f32x4*>(ws)[p * 4 + 3];
    const float f = r0[0] + gb4[0];
    float fj[4] = {r0[1], r0[2], r0[3], r1[0]};
    float fk[4][4];
    fk[0][0] = r1[1]; fk[0][1] = fk[1][0] = r1[2]; fk[0][2] = fk[2][0] = r1[3]; fk[0][3] = fk[3][0] = r2[0];
    fk[1][1] = r2[1]; fk[1][2] = fk[2][1] = r2[2]; fk[1][3] = fk[3][1] = r2[3];
    fk[2][2] = r3[0]; fk[2][3] = fk[3][2] = r3[1]; fk[3][3] = r3[2];

    float S, C;
    __sincosf(cth, &S, &C);
    const float E = __expf(f);
    const float r2v = cr * cr, S2 = S * S;
    const float GI1 = frcp(E), GI2 = frcp(r2v), GI3 = GI2 * frcp(S2);
    const float GIa[4] = {-1.f, GI1, GI2, GI3};

    float dg[4][4] = {};
    #pragma unroll
    for (int b = 0; b < 4; ++b) dg[1][b] = E * fj[b];
    dg[2][1] = 2.f * cr;
    dg[3][1] = 2.f * cr * S2;
    dg[3][2] = 2.f * r2v * S * C;
    const float ddrr3 = 2.f * S2, ddrth3 = 4.f * cr * S * C, ddthth3 = 2.f * r2v * (C * C - S2);

    auto dd = [&](int a, int b, int l) -> float {
        if (a == 1) return E * (fj[b] * fj[l] + fk[b][l]);
        if (a == 2) return (b == 1 && l == 1) ? 2.f : 0.f;
        if (a == 3) {
            if (b == 1 && l == 1) return ddrr3;
            if ((b == 1 && l == 2) || (b == 2 && l == 1)) return ddrth3;
            if (b == 2 && l == 2) return ddthth3;
        }
        return 0.f;
    };

    // Gm[i][mid][last] = Gamma^i_{mid,last} (symmetric in mid/last)
    float Gm[4][4][4];
    #pragma unroll
    for (int i = 0; i < 4; ++i)
        #pragma unroll
        for (int k = 0; k < 4; ++k)
            #pragma unroll
            for (int j = 0; j < 4; ++j)
                Gm[i][k][j] = 0.5f * GIa[i] * ((k == i ? dg[i][j] : 0.f)
                                             + (j == i ? dg[i][k] : 0.f)
                                             - (j == k ? dg[j][i] : 0.f));
    float T[4];
    #pragma unroll
    for (int m = 0; m < 4; ++m) {
        float s = 0.f;
        #pragma unroll
        for (int i = 0; i < 4; ++i) s += Gm[i][m][i];
        T[m] = s;
    }
    auto dGm = [&](int i, int k, int j, int l) -> float {
        const float P = (k == i ? dg[i][j] : 0.f) + (j == i ? dg[i][k] : 0.f) - (j == k ? dg[j][i] : 0.f);
        const float Q = (k == i ? dd(i, j, l) : 0.f) + (j == i ? dd(i, k, l) : 0.f) - (j == k ? dd(j, i, l) : 0.f);
        return 0.5f * (GIa[i] * Q - dg[i][l] * GIa[i] * GIa[i] * P);
    };

    float rc[4][4];
    #pragma unroll
    for (int j = 0; j < 4; ++j)
        #pragma unroll
        for (int k = 0; k < 4; ++k) {
            float t1 = 0.f, t2 = 0.f, t3 = 0.f, t4 = 0.f;
            #pragma unroll
            for (int m = 0; m < 4; ++m) t1 += Gm[m][j][k] * T[m];
            #pragma unroll
            for (int m = 0; m < 4; ++m)
                #pragma unroll
                for (int i = 0; i < 4; ++i) t2 += Gm[m][j][i] * Gm[i][m][k];
            #pragma unroll
            for (int i = 0; i < 4; ++i) { t3 += dGm(i, j, k, i); t4 += dGm(i, j, i, k); }
            rc[j][k] = t1 - t2 + t3 - t4;
        }

    const float R = -rc[0][0] + GI1 * rc[1][1] + GI2 * rc[2][2] + GI3 * rc[3][3];
    #pragma unroll
    for (int j = 0; j < 4; ++j) {
        f32x4 o;
        #pragma unroll
        for (int k = 0; k < 4; ++k)
            o[k] = GIa[j] * GIa[k] * rc[j][k] - ((j == k) ? 0.5f * R * GIa[j] : 0.f);
        reinterpret_cast<f32x4*>(out)[p * 4 + j] = o;
    }
}

extern "C" void kernel_launch(void* const* d_in, const int* in_sizes, int n_in,
                              void* d_out, int out_size, void* d_ws, size_t ws_size,
                              hipStream_t stream) {
    const float* coords = (const float*)d_in[0];
    const float* W1 = (const float*)d_in[1];
    const float* b1 = (const float*)d_in[2];
    const float* W2 = (const float*)d_in[3];
    const float* b2 = (const float*)d_in[4];
    const float* W3 = (const float*)d_in[5];
    const float* b3 = (const float*)d_in[6];
    const float* W4 = (const float*)d_in[7];
    const float* b4 = (const float*)d_in[8];
    const int B = in_sizes[0] / 4;

    hipLaunchKernelGGL(jet_kernel, dim3(NBLOCKS), dim3(BLOCK), 0, stream,
                       coords, W1, b1, W2, b2, W3, b3, W4,
                       (float*)d_ws, B);
    hipLaunchKernelGGL(einstein_epilogue, dim3((B + BLOCK - 1) / BLOCK), dim3(BLOCK), 0, stream,
                       coords, (const float*)d_ws, b4, (float*)d_out, B);
}